// Round 5
// baseline (1337.521 us; speedup 1.0000x reference)
//
#include <hip/hip_runtime.h>

typedef unsigned short u16;
typedef unsigned int u32;
typedef __attribute__((ext_vector_type(8))) short bf16x8;
typedef __attribute__((ext_vector_type(4))) float f32x4;
typedef __attribute__((ext_vector_type(16))) float f32x16;

#define DM 2048
#define SQ_SCALE (0.125f * 1.44269504089f)

__device__ __forceinline__ u16 f2bf(float f) {
  union { float f; u32 u; } v; v.f = f;
  u32 r = v.u + 0x7fffu + ((v.u >> 16) & 1u);
  return (u16)(r >> 16);
}
// pack two floats to (bf16(hi)<<16)|bf16(lo), round-half-up
__device__ __forceinline__ u32 pkrn(float lo, float hi) {
  union { float f; u32 u; } a, b; a.f = lo; b.f = hi;
  return ((a.u + 0x8000u) >> 16) | ((b.u + 0x8000u) & 0xffff0000u);
}
// hw packed cvt: dst = {bf16(lo) in [15:0], bf16(hi) in [31:16]} (RNE)
__device__ __forceinline__ u32 cvtpk(float lo, float hi) {
  u32 r;
  asm("v_cvt_pk_bf16_f32 %0, %1, %2" : "=v"(r) : "v"(lo), "v"(hi));
  return r;
}
__device__ __forceinline__ void gload16(const u16* g, u16* l) {
  __builtin_amdgcn_global_load_lds((const __attribute__((address_space(1))) void*)g,
                                   (__attribute__((address_space(3))) void*)l, 16, 0, 0);
}

// fp32 -> bf16 elementwise, 8 elems/thread; z selects tensor
__global__ __launch_bounds__(256) void cast3(const float* __restrict__ a0,
                                             const float* __restrict__ a1,
                                             const float* __restrict__ a2,
                                             u16* __restrict__ o0,
                                             u16* __restrict__ o1,
                                             u16* __restrict__ o2) {
  const float* in; u16* out;
  if (blockIdx.z == 0) { in = a0; out = o0; }
  else if (blockIdx.z == 1) { in = a1; out = o1; }
  else { in = a2; out = o2; }
  size_t i = ((size_t)blockIdx.x * 256 + threadIdx.x) * 8;
  float4 f0 = *(const float4*)(in + i);
  float4 f1 = *(const float4*)(in + i + 4);
  uint4 w = {pkrn(f0.x, f0.y), pkrn(f0.z, f0.w), pkrn(f1.x, f1.y), pkrn(f1.z, f1.w)};
  *(uint4*)(out + i) = w;
}

// fp32 [K][N] -> bf16 [N][K], 64x64 tiles
__global__ __launch_bounds__(256) void transpose_cast(const float* __restrict__ in,
                                                      u16* __restrict__ out,
                                                      int K, int N) {
  __shared__ u16 s[64][72];
  int n0 = blockIdx.x * 64, k0 = blockIdx.y * 64;
  int t = threadIdx.x;
  int r = t >> 2;
  int cc = (t & 3) * 16;
  const float* ip = in + (size_t)(k0 + r) * N + n0 + cc;
  u16 tmp[16];
#pragma unroll
  for (int i = 0; i < 16; i += 4) {
    float4 v = *(const float4*)(ip + i);
    tmp[i] = f2bf(v.x); tmp[i + 1] = f2bf(v.y);
    tmp[i + 2] = f2bf(v.z); tmp[i + 3] = f2bf(v.w);
  }
  *(uint4*)&s[r][cc] = *(uint4*)tmp;
  *(uint4*)&s[r][cc + 8] = *(uint4*)(tmp + 8);
  __syncthreads();
#pragma unroll
  for (int i = 0; i < 16; i++) tmp[i] = s[cc + i][r];
  u16* op = out + (size_t)(n0 + r) * K + k0 + cc;
  *(uint4*)op = *(uint4*)tmp;
  *(uint4*)(op + 8) = *(uint4*)(tmp + 8);
}

// V^T precompute: kvb [b*2048+t][1024] (V at 512+g*64+d) -> vtb [b*8+g][64][2048]
__global__ __launch_bounds__(256) void transpose_v(const u16* __restrict__ kvb,
                                                   u16* __restrict__ vtb) {
  __shared__ u16 s[64][72];
  int bg = blockIdx.y;
  int t0 = blockIdx.x * 64;
  int t = threadIdx.x;
  int r = t >> 2;
  int cc = (t & 3) * 16;
  const u16* ip = kvb + ((size_t)(bg >> 3) * 2048 + t0 + r) * 1024 + 512 + (bg & 7) * 64 + cc;
  *(uint4*)&s[r][cc] = *(const uint4*)ip;
  *(uint4*)&s[r][cc + 8] = *(const uint4*)(ip + 8);
  __syncthreads();
  u16 tmp[16];
#pragma unroll
  for (int i = 0; i < 16; i++) tmp[i] = s[cc + i][r];
  u16* op = vtb + (size_t)bg * 64 * 2048 + (size_t)r * 2048 + t0 + cc;
  *(uint4*)op = *(uint4*)tmp;
  *(uint4*)(op + 8) = *(uint4*)(tmp + 8);
}

// Fused QKV projection: C = A @ Bt^T + bias. A selected by n-tile.
// N logical 3072: [0,2048) Q -> qhb (scaled), [2048,2560) K, [2560,3072) V -> kvb.
__global__ __launch_bounds__(256) void gemm_proj(const u16* __restrict__ qb,
                                                 const u16* __restrict__ kb,
                                                 const u16* __restrict__ vb,
                                                 const u16* __restrict__ Bt,
                                                 const float* __restrict__ bqp,
                                                 const float* __restrict__ bkp,
                                                 const float* __restrict__ bvp,
                                                 u16* __restrict__ qhb,
                                                 u16* __restrict__ kvb) {
  __shared__ u16 As[128 * 32];
  __shared__ u16 Bs[128 * 32];
  int n0 = blockIdx.x * 128, m0 = blockIdx.y * 128;
  const u16* A; const float* bias; u16* C; int cw, bofs; float esc;
  if (n0 < 2048)      { A = qb; bias = bqp; C = qhb; cw = 2048; bofs = 0;    esc = SQ_SCALE; }
  else if (n0 < 2560) { A = kb; bias = bkp; C = kvb; cw = 1024; bofs = 2048; esc = 1.0f; }
  else                { A = vb; bias = bvp; C = kvb; cw = 1024; bofs = 2560; esc = 1.0f; }
  int ccol0 = (n0 < 2048) ? n0 : (n0 - 2048);

  int tid = threadIdx.x, wave = tid >> 6, lane = tid & 63;
  int lq = lane & 15, quad = lane >> 4;
  int wm = (wave & 1) * 64, wn = (wave >> 1) * 64;

  f32x4 zero = {0.f, 0.f, 0.f, 0.f};
  f32x4 acc[4][4];
#pragma unroll
  for (int i = 0; i < 4; i++)
#pragma unroll
    for (int j = 0; j < 4; j++) acc[i][j] = zero;

  const u16* gA = A + (size_t)(m0 + wave * 16 + (lane >> 2)) * 2048 + (lane & 3) * 8;
  const u16* gB = Bt + (size_t)(n0 + wave * 16 + (lane >> 2)) * 2048 + (lane & 3) * 8;
  u16* lA0 = &As[(wave * 16) * 32];
  u16* lA1 = &As[(64 + wave * 16) * 32];
  u16* lB0 = &Bs[(wave * 16) * 32];
  u16* lB1 = &Bs[(64 + wave * 16) * 32];

  for (int k0 = 0; k0 < 2048; k0 += 32) {
    __syncthreads();
    gload16(gA + k0, lA0);
    gload16(gA + (size_t)64 * 2048 + k0, lA1);
    gload16(gB + k0, lB0);
    gload16(gB + (size_t)64 * 2048 + k0, lB1);
    __syncthreads();
    bf16x8 af[4], bf[4];
#pragma unroll
    for (int i = 0; i < 4; i++) af[i] = *(const bf16x8*)&As[(wm + i * 16 + lq) * 32 + quad * 8];
#pragma unroll
    for (int j = 0; j < 4; j++) bf[j] = *(const bf16x8*)&Bs[(wn + j * 16 + lq) * 32 + quad * 8];
#pragma unroll
    for (int i = 0; i < 4; i++)
#pragma unroll
      for (int j = 0; j < 4; j++)
        acc[i][j] = __builtin_amdgcn_mfma_f32_16x16x32_bf16(af[i], bf[j], acc[i][j], 0, 0, 0);
  }
#pragma unroll
  for (int j = 0; j < 4; j++) {
    int nglob = n0 + wn + j * 16 + lq;
    float bv = bias[nglob - bofs];
    int col = ccol0 + wn + j * 16 + lq;
#pragma unroll
    for (int i = 0; i < 4; i++) {
#pragma unroll
      for (int rg = 0; rg < 4; rg++) {
        int row = m0 + wm + i * 16 + quad * 4 + rg;
        C[(size_t)row * cw + col] = f2bf((acc[i][j][rg] + bv) * esc);
      }
    }
  }
}

// O projection: fp32 C out
__global__ __launch_bounds__(256) void gemm_o(const u16* __restrict__ A,
                                              const u16* __restrict__ Bt,
                                              const float* __restrict__ bias,
                                              float* __restrict__ C) {
  __shared__ u16 As[128 * 32];
  __shared__ u16 Bs[128 * 32];
  int n0 = blockIdx.x * 128, m0 = blockIdx.y * 128;
  int tid = threadIdx.x, wave = tid >> 6, lane = tid & 63;
  int lq = lane & 15, quad = lane >> 4;
  int wm = (wave & 1) * 64, wn = (wave >> 1) * 64;

  f32x4 zero = {0.f, 0.f, 0.f, 0.f};
  f32x4 acc[4][4];
#pragma unroll
  for (int i = 0; i < 4; i++)
#pragma unroll
    for (int j = 0; j < 4; j++) acc[i][j] = zero;

  const u16* gA = A + (size_t)(m0 + wave * 16 + (lane >> 2)) * 2048 + (lane & 3) * 8;
  const u16* gB = Bt + (size_t)(n0 + wave * 16 + (lane >> 2)) * 2048 + (lane & 3) * 8;
  u16* lA0 = &As[(wave * 16) * 32];
  u16* lA1 = &As[(64 + wave * 16) * 32];
  u16* lB0 = &Bs[(wave * 16) * 32];
  u16* lB1 = &Bs[(64 + wave * 16) * 32];

  for (int k0 = 0; k0 < 2048; k0 += 32) {
    __syncthreads();
    gload16(gA + k0, lA0);
    gload16(gA + (size_t)64 * 2048 + k0, lA1);
    gload16(gB + k0, lB0);
    gload16(gB + (size_t)64 * 2048 + k0, lB1);
    __syncthreads();
    bf16x8 af[4], bf[4];
#pragma unroll
    for (int i = 0; i < 4; i++) af[i] = *(const bf16x8*)&As[(wm + i * 16 + lq) * 32 + quad * 8];
#pragma unroll
    for (int j = 0; j < 4; j++) bf[j] = *(const bf16x8*)&Bs[(wn + j * 16 + lq) * 32 + quad * 8];
#pragma unroll
    for (int i = 0; i < 4; i++)
#pragma unroll
      for (int j = 0; j < 4; j++)
        acc[i][j] = __builtin_amdgcn_mfma_f32_16x16x32_bf16(af[i], bf[j], acc[i][j], 0, 0, 0);
  }
#pragma unroll
  for (int j = 0; j < 4; j++) {
    int col = n0 + wn + j * 16 + lq;
    float bv = bias[col];
#pragma unroll
    for (int i = 0; i < 4; i++) {
#pragma unroll
      for (int rg = 0; rg < 4; rg++) {
        int row = m0 + wm + i * 16 + quad * 4 + rg;
        C[(size_t)row * 2048 + col] = acc[i][j][rg] + bv;
      }
    }
  }
}

// Flash attention v4: 32x32 MFMA, S^T = K.Q^T, PV via xor-32 exchange.
// 512-thread blocks, 8 waves = 4 s-tiles x 2 T-halves (t in [0,1024) / [1024,2048)).
// Softmax has no running max (pure exp-sum) -> partial (o,l) over disjoint
// t-ranges combine linearly; half 1 deposits partials in LDS (unioned over the
// dead K/V buffers), half 0 merges+stores. 1024 blocks x 8 waves = 32 waves/CU
// = 8 waves/SIMD (R3 limiter: Occ 31%, VALU 56%, Mfma 29% -- wave-starved).
__global__ __launch_bounds__(512, 8) void attn2(const u16* __restrict__ qh,
                                                const u16* __restrict__ kvb,
                                                const u16* __restrict__ vtb,
                                                u16* __restrict__ out) {
  __shared__ union {
    struct { u16 Ks[2][32][72]; u16 Vs[2][64][40]; } s;     // 19456 B (loop)
    struct { float Ox[4][32][64]; float Lx[4][32]; float Ls[4][32]; } e;  // 33792 B (epilogue)
  } sm;
  int flat = blockIdx.x + (blockIdx.y << 4);
  int w = ((flat & 7) << 7) + (flat >> 3);   // bijective: 1024 blocks, 128/XCD
  int head = w >> 4;
  int b = head >> 5, g = (head >> 2) & 7, h = head & 3;
  int tid = threadIdx.x, wave = tid >> 6, lane = tid & 63;
  int thalf = wave >> 2, swave = wave & 3;
  int lh = lane & 31, hi = lane >> 5;
  const int qoff = (g * 4 + h) * 64;
  const int koff = g * 64;
  int sBase = (w & 15) * 128 + swave * 32;

  // Q as B-operand (Q^T): lane n=s=lh, k=d = st*16 + hi*8 + j
  bf16x8 qf[4];
#pragma unroll
  for (int st = 0; st < 4; st++)
    qf[st] = *(const bf16x8*)(qh + (size_t)(b * 2048 + sBase + lh) * DM +
                              qoff + st * 16 + hi * 8);

  f32x16 o_acc[2];
#pragma unroll
  for (int db = 0; db < 2; db++)
#pragma unroll
    for (int r = 0; r < 16; r++) o_acc[db][r] = 0.f;
  float l_acc = 0.f;

  int htid = tid & 255;
  int sr = htid >> 3, sc = (htid & 7) * 8;  // K staging (per half)
  int vd = htid >> 2, vc = (htid & 3) * 8;  // V^T staging (per half)
  const u16* kbase = kvb + (size_t)b * 2048 * 1024 + koff + (size_t)thalf * 1024 * 1024;
  const u16* vbase = vtb + (size_t)(head >> 2) * 64 * 2048 + (size_t)vd * 2048 + thalf * 1024;

  uint4 kreg = *(const uint4*)(kbase + (size_t)sr * 1024 + sc);
  uint4 vreg = *(const uint4*)(vbase + vc);

  for (int t0 = 0; t0 < 1024; t0 += 32) {
    __syncthreads();
    *(uint4*)&sm.s.Ks[thalf][sr][sc] = kreg;
    *(uint4*)&sm.s.Vs[thalf][vd][vc] = vreg;
    __syncthreads();
    int tn = (t0 + 32 < 1024) ? t0 + 32 : 0;
    kreg = *(const uint4*)(kbase + (size_t)(tn + sr) * 1024 + sc);
    vreg = *(const uint4*)(vbase + tn + vc);

    bf16x8 kf[4], vf[2][2];
#pragma unroll
    for (int st = 0; st < 4; st++) kf[st] = *(const bf16x8*)&sm.s.Ks[thalf][lh][st * 16 + hi * 8];
#pragma unroll
    for (int T = 0; T < 2; T++)
#pragma unroll
      for (int db = 0; db < 2; db++)
        vf[T][db] = *(const bf16x8*)&sm.s.Vs[thalf][db * 32 + lh][T * 16 + hi * 8];

    f32x16 st_acc;
#pragma unroll
    for (int r = 0; r < 16; r++) st_acc[r] = 0.f;
    __builtin_amdgcn_s_setprio(1);
#pragma unroll
    for (int st = 0; st < 4; st++)
      st_acc = __builtin_amdgcn_mfma_f32_32x32x16_bf16(kf[st], qf[st], st_acc, 0, 0, 0);
    __builtin_amdgcn_s_setprio(0);
    // S^T: lane holds col s=lh, rows t=(r&3)+8*(r>>2)+4*hi
    float pr[16];
#pragma unroll
    for (int r = 0; r < 16; r++) pr[r] = __builtin_amdgcn_exp2f(st_acc[r]);
    float s0 = ((pr[0] + pr[1]) + (pr[2] + pr[3])) + ((pr[4] + pr[5]) + (pr[6] + pr[7]));
    float s1 = ((pr[8] + pr[9]) + (pr[10] + pr[11])) + ((pr[12] + pr[13]) + (pr[14] + pr[15]));
    l_acc += s0 + s1;
    u32 pk[8];
#pragma unroll
    for (int a = 0; a < 4; a++) {
      pk[2 * a] = cvtpk(pr[4 * a], pr[4 * a + 1]);
      pk[2 * a + 1] = cvtpk(pr[4 * a + 2], pr[4 * a + 3]);
    }
#pragma unroll
    for (int T = 0; T < 2; T++) {
      // A-operand for PV needs t = 16T + 8*hi + j; exchange halves via xor-32
      u32 E0 = hi ? pk[4 * T] : pk[4 * T + 2];
      u32 E1 = hi ? pk[4 * T + 1] : pk[4 * T + 3];
      u32 X0 = __shfl_xor(E0, 32);
      u32 X1 = __shfl_xor(E1, 32);
      union { u32 u[4]; bf16x8 v; } af;
      af.u[0] = hi ? X0 : pk[4 * T];
      af.u[1] = hi ? X1 : pk[4 * T + 1];
      af.u[2] = hi ? pk[4 * T + 2] : X0;
      af.u[3] = hi ? pk[4 * T + 3] : X1;
      __builtin_amdgcn_s_setprio(1);
#pragma unroll
      for (int db = 0; db < 2; db++)
        o_acc[db] = __builtin_amdgcn_mfma_f32_32x32x16_bf16(af.v, vf[T][db], o_acc[db], 0, 0, 0);
      __builtin_amdgcn_s_setprio(0);
    }
  }

  // cross-half merge: half 1 deposits (o,l); half 0 merges, normalizes, stores
  float lt = l_acc + __shfl_xor(l_acc, 32);
  __syncthreads();   // K/V LDS dead; safe to overwrite with exchange buffers
  if (thalf == 1) {
#pragma unroll
    for (int db = 0; db < 2; db++)
#pragma unroll
      for (int r = 0; r < 16; r++) {
        int srow = (r & 3) + 8 * (r >> 2) + 4 * hi;
        sm.e.Ox[swave][srow][db * 32 + lh] = o_acc[db][r];
      }
    if (hi == 0) sm.e.Lx[swave][lh] = lt;
  }
  __syncthreads();
  if (thalf == 0) {
    lt += sm.e.Lx[swave][lh];
#pragma unroll
    for (int db = 0; db < 2; db++)
#pragma unroll
      for (int r = 0; r < 16; r++) {
        int srow = (r & 3) + 8 * (r >> 2) + 4 * hi;
        o_acc[db][r] += sm.e.Ox[swave][srow][db * 32 + lh];
      }
    sm.e.Ls[swave][lh] = 1.0f / lt;
    __builtin_amdgcn_wave_barrier();
    f32x4 inv[4];
#pragma unroll
    for (int a = 0; a < 4; a++) inv[a] = *(const f32x4*)&sm.e.Ls[swave][8 * a + 4 * hi];
#pragma unroll
    for (int db = 0; db < 2; db++) {
#pragma unroll
      for (int r = 0; r < 16; r++) {
        int srow = (r & 3) + 8 * (r >> 2) + 4 * hi;
        size_t o = (size_t)(b * 2048 + sBase + srow) * DM + qoff + db * 32 + lh;
        out[o] = f2bf(o_acc[db][r] * inv[r >> 2][r & 3]);
      }
    }
  }
}

extern "C" void kernel_launch(void* const* d_in, const int* in_sizes, int n_in,
                              void* d_out, int out_size, void* d_ws, size_t ws_size,
                              hipStream_t stream) {
  const float* q  = (const float*)d_in[0];
  const float* k  = (const float*)d_in[1];
  const float* v  = (const float*)d_in[2];
  const float* Wq = (const float*)d_in[3];
  const float* bq = (const float*)d_in[4];
  const float* Wk = (const float*)d_in[5];
  const float* bk = (const float*)d_in[6];
  const float* Wv = (const float*)d_in[7];
  const float* bv = (const float*)d_in[8];
  const float* Wo = (const float*)d_in[9];
  const float* bo = (const float*)d_in[10];

  u16* p = (u16*)d_ws;
  u16* WqkvT = p; p += (size_t)3072 * 2048;   // rows: 0-2047 Wq^T, 2048-2559 Wk^T, 2560-3071 Wv^T
  u16* WoT   = p; p += (size_t)2048 * 2048;
  u16* qb    = p; p += (size_t)4096 * 2048;   // bf16 casts of q/k/v; att aliases qb
  u16* kb    = p; p += (size_t)4096 * 2048;
  u16* vb    = p; p += (size_t)4096 * 2048;
  u16* qhb   = p; p += (size_t)4096 * 2048;
  u16* kvb   = p; p += (size_t)4096 * 1024;
  u16* vtb   = p; p += (size_t)16 * 64 * 2048;
  u16* att   = qb;  // reuse: qb dead after gemm_proj

  cast3<<<dim3(4096, 1, 3), 256, 0, stream>>>(q, k, v, qb, kb, vb);

  transpose_cast<<<dim3(32, 32), 256, 0, stream>>>(Wq, WqkvT, 2048, 2048);
  transpose_cast<<<dim3(8, 32), 256, 0, stream>>>(Wk, WqkvT + (size_t)2048 * 2048, 2048, 512);
  transpose_cast<<<dim3(8, 32), 256, 0, stream>>>(Wv, WqkvT + (size_t)2560 * 2048, 2048, 512);
  transpose_cast<<<dim3(32, 32), 256, 0, stream>>>(Wo, WoT, 2048, 2048);

  gemm_proj<<<dim3(24, 32), 256, 0, stream>>>(qb, kb, vb, WqkvT, bq, bk, bv, qhb, kvb);

  transpose_v<<<dim3(32, 16), 256, 0, stream>>>(kvb, vtb);

  attn2<<<dim3(16, 64), 512, 0, stream>>>(qhb, kvb, vtb, att);

  gemm_o<<<dim3(16, 32), 256, 0, stream>>>(att, WoT, bo, (float*)d_out);
}

// Round 6
// 519.206 us; speedup vs baseline: 2.5761x; 2.5761x over previous
//
#include <hip/hip_runtime.h>

typedef unsigned short u16;
typedef unsigned int u32;
typedef __attribute__((ext_vector_type(8))) short bf16x8;
typedef __attribute__((ext_vector_type(4))) float f32x4;
typedef __attribute__((ext_vector_type(16))) float f32x16;

#define DM 2048
#define SQ_SCALE (0.125f * 1.44269504089f)

__device__ __forceinline__ u16 f2bf(float f) {
  union { float f; u32 u; } v; v.f = f;
  u32 r = v.u + 0x7fffu + ((v.u >> 16) & 1u);
  return (u16)(r >> 16);
}
// pack two floats to (bf16(hi)<<16)|bf16(lo), round-half-up
__device__ __forceinline__ u32 pkrn(float lo, float hi) {
  union { float f; u32 u; } a, b; a.f = lo; b.f = hi;
  return ((a.u + 0x8000u) >> 16) | ((b.u + 0x8000u) & 0xffff0000u);
}
// hw packed cvt: dst = {bf16(lo) in [15:0], bf16(hi) in [31:16]} (RNE)
__device__ __forceinline__ u32 cvtpk(float lo, float hi) {
  u32 r;
  asm("v_cvt_pk_bf16_f32 %0, %1, %2" : "=v"(r) : "v"(lo), "v"(hi));
  return r;
}
__device__ __forceinline__ void gload16(const u16* g, u16* l) {
  __builtin_amdgcn_global_load_lds((const __attribute__((address_space(1))) void*)g,
                                   (__attribute__((address_space(3))) void*)l, 16, 0, 0);
}

// fp32 -> bf16 elementwise, 8 elems/thread; z selects tensor
__global__ __launch_bounds__(256) void cast3(const float* __restrict__ a0,
                                             const float* __restrict__ a1,
                                             const float* __restrict__ a2,
                                             u16* __restrict__ o0,
                                             u16* __restrict__ o1,
                                             u16* __restrict__ o2) {
  const float* in; u16* out;
  if (blockIdx.z == 0) { in = a0; out = o0; }
  else if (blockIdx.z == 1) { in = a1; out = o1; }
  else { in = a2; out = o2; }
  size_t i = ((size_t)blockIdx.x * 256 + threadIdx.x) * 8;
  float4 f0 = *(const float4*)(in + i);
  float4 f1 = *(const float4*)(in + i + 4);
  uint4 w = {pkrn(f0.x, f0.y), pkrn(f0.z, f0.w), pkrn(f1.x, f1.y), pkrn(f1.z, f1.w)};
  *(uint4*)(out + i) = w;
}

// fp32 [K][N] -> bf16 [N][K], 64x64 tiles
__global__ __launch_bounds__(256) void transpose_cast(const float* __restrict__ in,
                                                      u16* __restrict__ out,
                                                      int K, int N) {
  __shared__ u16 s[64][72];
  int n0 = blockIdx.x * 64, k0 = blockIdx.y * 64;
  int t = threadIdx.x;
  int r = t >> 2;
  int cc = (t & 3) * 16;
  const float* ip = in + (size_t)(k0 + r) * N + n0 + cc;
  u16 tmp[16];
#pragma unroll
  for (int i = 0; i < 16; i += 4) {
    float4 v = *(const float4*)(ip + i);
    tmp[i] = f2bf(v.x); tmp[i + 1] = f2bf(v.y);
    tmp[i + 2] = f2bf(v.z); tmp[i + 3] = f2bf(v.w);
  }
  *(uint4*)&s[r][cc] = *(uint4*)tmp;
  *(uint4*)&s[r][cc + 8] = *(uint4*)(tmp + 8);
  __syncthreads();
#pragma unroll
  for (int i = 0; i < 16; i++) tmp[i] = s[cc + i][r];
  u16* op = out + (size_t)(n0 + r) * K + k0 + cc;
  *(uint4*)op = *(uint4*)tmp;
  *(uint4*)(op + 8) = *(uint4*)(tmp + 8);
}

// Fused QKV projection: C = A @ Bt^T + bias. A selected by n-tile.
// N logical 3072: [0,2048) Q -> qhb (scaled), [2048,2560) K -> kvb cols 0-511,
// [2560,3072) V -> V^T written DIRECTLY to vtb[(b*8+g)][d][t] (transpose_v fused).
__global__ __launch_bounds__(256) void gemm_proj(const u16* __restrict__ qb,
                                                 const u16* __restrict__ kb,
                                                 const u16* __restrict__ vb,
                                                 const u16* __restrict__ Bt,
                                                 const float* __restrict__ bqp,
                                                 const float* __restrict__ bkp,
                                                 const float* __restrict__ bvp,
                                                 u16* __restrict__ qhb,
                                                 u16* __restrict__ kvb,
                                                 u16* __restrict__ vtb) {
  __shared__ u16 As[128 * 32];
  __shared__ u16 Bs[128 * 32];
  int n0 = blockIdx.x * 128, m0 = blockIdx.y * 128;
  const u16* A; const float* bias; u16* C; int cw, bofs; float esc;
  if (n0 < 2048)      { A = qb; bias = bqp; C = qhb; cw = 2048; bofs = 0;    esc = SQ_SCALE; }
  else if (n0 < 2560) { A = kb; bias = bkp; C = kvb; cw = 1024; bofs = 2048; esc = 1.0f; }
  else                { A = vb; bias = bvp; C = kvb; cw = 1024; bofs = 2560; esc = 1.0f; }
  int ccol0 = (n0 < 2048) ? n0 : (n0 - 2048);

  int tid = threadIdx.x, wave = tid >> 6, lane = tid & 63;
  int lq = lane & 15, quad = lane >> 4;
  int wm = (wave & 1) * 64, wn = (wave >> 1) * 64;

  f32x4 zero = {0.f, 0.f, 0.f, 0.f};
  f32x4 acc[4][4];
#pragma unroll
  for (int i = 0; i < 4; i++)
#pragma unroll
    for (int j = 0; j < 4; j++) acc[i][j] = zero;

  const u16* gA = A + (size_t)(m0 + wave * 16 + (lane >> 2)) * 2048 + (lane & 3) * 8;
  const u16* gB = Bt + (size_t)(n0 + wave * 16 + (lane >> 2)) * 2048 + (lane & 3) * 8;
  u16* lA0 = &As[(wave * 16) * 32];
  u16* lA1 = &As[(64 + wave * 16) * 32];
  u16* lB0 = &Bs[(wave * 16) * 32];
  u16* lB1 = &Bs[(64 + wave * 16) * 32];

  for (int k0 = 0; k0 < 2048; k0 += 32) {
    __syncthreads();
    gload16(gA + k0, lA0);
    gload16(gA + (size_t)64 * 2048 + k0, lA1);
    gload16(gB + k0, lB0);
    gload16(gB + (size_t)64 * 2048 + k0, lB1);
    __syncthreads();
    bf16x8 af[4], bf[4];
#pragma unroll
    for (int i = 0; i < 4; i++) af[i] = *(const bf16x8*)&As[(wm + i * 16 + lq) * 32 + quad * 8];
#pragma unroll
    for (int j = 0; j < 4; j++) bf[j] = *(const bf16x8*)&Bs[(wn + j * 16 + lq) * 32 + quad * 8];
#pragma unroll
    for (int i = 0; i < 4; i++)
#pragma unroll
      for (int j = 0; j < 4; j++)
        acc[i][j] = __builtin_amdgcn_mfma_f32_16x16x32_bf16(af[i], bf[j], acc[i][j], 0, 0, 0);
  }
  if (n0 >= 2560) {
    // V: write V^T directly. col cv in [0,512): g=cv>>6, d=cv&63; rows are t.
    // rg 0..3 -> consecutive t -> 8B contiguous stores (t%4==0 -> 8B aligned).
#pragma unroll
    for (int j = 0; j < 4; j++) {
      int cv = (n0 - 2560) + wn + j * 16 + lq;
      float bvv = bias[cv];
      u16* vout = vtb + (size_t)((cv >> 6) * 64 + (cv & 63)) * 2048;
#pragma unroll
      for (int i = 0; i < 4; i++) {
        int row = m0 + wm + i * 16 + quad * 4;
        int bb = row >> 11, tt = row & 2047;
        u16 w4[4];
#pragma unroll
        for (int rg = 0; rg < 4; rg++) w4[rg] = f2bf(acc[i][j][rg] + bvv);
        *(uint2*)(vout + (size_t)bb * 8 * 64 * 2048 + tt) = *(uint2*)w4;
      }
    }
  } else {
#pragma unroll
    for (int j = 0; j < 4; j++) {
      int nglob = n0 + wn + j * 16 + lq;
      float bv = bias[nglob - bofs];
      int col = ccol0 + wn + j * 16 + lq;
#pragma unroll
      for (int i = 0; i < 4; i++) {
#pragma unroll
        for (int rg = 0; rg < 4; rg++) {
          int row = m0 + wm + i * 16 + quad * 4 + rg;
          C[(size_t)row * cw + col] = f2bf((acc[i][j][rg] + bv) * esc);
        }
      }
    }
  }
}

// O projection: fp32 C out
__global__ __launch_bounds__(256) void gemm_o(const u16* __restrict__ A,
                                              const u16* __restrict__ Bt,
                                              const float* __restrict__ bias,
                                              float* __restrict__ C) {
  __shared__ u16 As[128 * 32];
  __shared__ u16 Bs[128 * 32];
  int n0 = blockIdx.x * 128, m0 = blockIdx.y * 128;
  int tid = threadIdx.x, wave = tid >> 6, lane = tid & 63;
  int lq = lane & 15, quad = lane >> 4;
  int wm = (wave & 1) * 64, wn = (wave >> 1) * 64;

  f32x4 zero = {0.f, 0.f, 0.f, 0.f};
  f32x4 acc[4][4];
#pragma unroll
  for (int i = 0; i < 4; i++)
#pragma unroll
    for (int j = 0; j < 4; j++) acc[i][j] = zero;

  const u16* gA = A + (size_t)(m0 + wave * 16 + (lane >> 2)) * 2048 + (lane & 3) * 8;
  const u16* gB = Bt + (size_t)(n0 + wave * 16 + (lane >> 2)) * 2048 + (lane & 3) * 8;
  u16* lA0 = &As[(wave * 16) * 32];
  u16* lA1 = &As[(64 + wave * 16) * 32];
  u16* lB0 = &Bs[(wave * 16) * 32];
  u16* lB1 = &Bs[(64 + wave * 16) * 32];

  for (int k0 = 0; k0 < 2048; k0 += 32) {
    __syncthreads();
    gload16(gA + k0, lA0);
    gload16(gA + (size_t)64 * 2048 + k0, lA1);
    gload16(gB + k0, lB0);
    gload16(gB + (size_t)64 * 2048 + k0, lB1);
    __syncthreads();
    bf16x8 af[4], bf[4];
#pragma unroll
    for (int i = 0; i < 4; i++) af[i] = *(const bf16x8*)&As[(wm + i * 16 + lq) * 32 + quad * 8];
#pragma unroll
    for (int j = 0; j < 4; j++) bf[j] = *(const bf16x8*)&Bs[(wn + j * 16 + lq) * 32 + quad * 8];
#pragma unroll
    for (int i = 0; i < 4; i++)
#pragma unroll
      for (int j = 0; j < 4; j++)
        acc[i][j] = __builtin_amdgcn_mfma_f32_16x16x32_bf16(af[i], bf[j], acc[i][j], 0, 0, 0);
  }
#pragma unroll
  for (int j = 0; j < 4; j++) {
    int col = n0 + wn + j * 16 + lq;
    float bv = bias[col];
#pragma unroll
    for (int i = 0; i < 4; i++) {
#pragma unroll
      for (int rg = 0; rg < 4; rg++) {
        int row = m0 + wm + i * 16 + quad * 4 + rg;
        C[(size_t)row * 2048 + col] = acc[i][j][rg] + bv;
      }
    }
  }
}

// Flash attention v6: v4 structure (512 thr, 8 waves = 4 s-tiles x 2 T-halves),
// NO min-wave pin (R5's __launch_bounds__(512,8) forced VGPR=32 -> full spill,
// 5 GB scratch traffic, 10x regression). Compiler free to use ~72-90 VGPR ->
// 3 blocks/CU = 24 waves/CU (vs R3's 16). Partial (o,l) over disjoint t-ranges
// combine linearly (no running max); half 1 deposits in LDS, half 0 merges.
__global__ __launch_bounds__(512) void attn2(const u16* __restrict__ qh,
                                             const u16* __restrict__ kvb,
                                             const u16* __restrict__ vtb,
                                             u16* __restrict__ out) {
  __shared__ union {
    struct { u16 Ks[2][32][72]; u16 Vs[2][64][40]; } s;     // 19456 B (loop)
    struct { float Ox[4][32][64]; float Lx[4][32]; float Ls[4][32]; } e;  // 33792 B (epilogue)
  } sm;
  int flat = blockIdx.x + (blockIdx.y << 4);
  int w = ((flat & 7) << 7) + (flat >> 3);   // bijective: 1024 blocks, 128/XCD
  int head = w >> 4;
  int b = head >> 5, g = (head >> 2) & 7, h = head & 3;
  int tid = threadIdx.x, wave = tid >> 6, lane = tid & 63;
  int thalf = wave >> 2, swave = wave & 3;
  int lh = lane & 31, hi = lane >> 5;
  const int qoff = (g * 4 + h) * 64;
  const int koff = g * 64;
  int sBase = (w & 15) * 128 + swave * 32;

  // Q as B-operand (Q^T): lane n=s=lh, k=d = st*16 + hi*8 + j
  bf16x8 qf[4];
#pragma unroll
  for (int st = 0; st < 4; st++)
    qf[st] = *(const bf16x8*)(qh + (size_t)(b * 2048 + sBase + lh) * DM +
                              qoff + st * 16 + hi * 8);

  f32x16 o_acc[2];
#pragma unroll
  for (int db = 0; db < 2; db++)
#pragma unroll
    for (int r = 0; r < 16; r++) o_acc[db][r] = 0.f;
  float l_acc = 0.f;

  int htid = tid & 255;
  int sr = htid >> 3, sc = (htid & 7) * 8;  // K staging (per half)
  int vd = htid >> 2, vc = (htid & 3) * 8;  // V^T staging (per half)
  const u16* kbase = kvb + (size_t)b * 2048 * 1024 + koff + (size_t)thalf * 1024 * 1024;
  const u16* vbase = vtb + (size_t)(head >> 2) * 64 * 2048 + (size_t)vd * 2048 + thalf * 1024;

  uint4 kreg = *(const uint4*)(kbase + (size_t)sr * 1024 + sc);
  uint4 vreg = *(const uint4*)(vbase + vc);

  for (int t0 = 0; t0 < 1024; t0 += 32) {
    __syncthreads();
    *(uint4*)&sm.s.Ks[thalf][sr][sc] = kreg;
    *(uint4*)&sm.s.Vs[thalf][vd][vc] = vreg;
    __syncthreads();
    int tn = (t0 + 32 < 1024) ? t0 + 32 : 0;
    kreg = *(const uint4*)(kbase + (size_t)(tn + sr) * 1024 + sc);
    vreg = *(const uint4*)(vbase + tn + vc);

    bf16x8 kf[4], vf[2][2];
#pragma unroll
    for (int st = 0; st < 4; st++) kf[st] = *(const bf16x8*)&sm.s.Ks[thalf][lh][st * 16 + hi * 8];
#pragma unroll
    for (int T = 0; T < 2; T++)
#pragma unroll
      for (int db = 0; db < 2; db++)
        vf[T][db] = *(const bf16x8*)&sm.s.Vs[thalf][db * 32 + lh][T * 16 + hi * 8];

    f32x16 st_acc;
#pragma unroll
    for (int r = 0; r < 16; r++) st_acc[r] = 0.f;
    __builtin_amdgcn_s_setprio(1);
#pragma unroll
    for (int st = 0; st < 4; st++)
      st_acc = __builtin_amdgcn_mfma_f32_32x32x16_bf16(kf[st], qf[st], st_acc, 0, 0, 0);
    __builtin_amdgcn_s_setprio(0);
    // S^T: lane holds col s=lh, rows t=(r&3)+8*(r>>2)+4*hi
    float pr[16];
#pragma unroll
    for (int r = 0; r < 16; r++) pr[r] = __builtin_amdgcn_exp2f(st_acc[r]);
    float s0 = ((pr[0] + pr[1]) + (pr[2] + pr[3])) + ((pr[4] + pr[5]) + (pr[6] + pr[7]));
    float s1 = ((pr[8] + pr[9]) + (pr[10] + pr[11])) + ((pr[12] + pr[13]) + (pr[14] + pr[15]));
    l_acc += s0 + s1;
    u32 pk[8];
#pragma unroll
    for (int a = 0; a < 4; a++) {
      pk[2 * a] = cvtpk(pr[4 * a], pr[4 * a + 1]);
      pk[2 * a + 1] = cvtpk(pr[4 * a + 2], pr[4 * a + 3]);
    }
#pragma unroll
    for (int T = 0; T < 2; T++) {
      // A-operand for PV needs t = 16T + 8*hi + j; exchange halves via xor-32
      u32 E0 = hi ? pk[4 * T] : pk[4 * T + 2];
      u32 E1 = hi ? pk[4 * T + 1] : pk[4 * T + 3];
      u32 X0 = __shfl_xor(E0, 32);
      u32 X1 = __shfl_xor(E1, 32);
      union { u32 u[4]; bf16x8 v; } af;
      af.u[0] = hi ? X0 : pk[4 * T];
      af.u[1] = hi ? X1 : pk[4 * T + 1];
      af.u[2] = hi ? pk[4 * T + 2] : X0;
      af.u[3] = hi ? pk[4 * T + 3] : X1;
      __builtin_amdgcn_s_setprio(1);
#pragma unroll
      for (int db = 0; db < 2; db++)
        o_acc[db] = __builtin_amdgcn_mfma_f32_32x32x16_bf16(af.v, vf[T][db], o_acc[db], 0, 0, 0);
      __builtin_amdgcn_s_setprio(0);
    }
  }

  // cross-half merge: half 1 deposits (o,l); half 0 merges, normalizes, stores
  float lt = l_acc + __shfl_xor(l_acc, 32);
  __syncthreads();   // K/V LDS dead; safe to overwrite with exchange buffers
  if (thalf == 1) {
#pragma unroll
    for (int db = 0; db < 2; db++)
#pragma unroll
      for (int r = 0; r < 16; r++) {
        int srow = (r & 3) + 8 * (r >> 2) + 4 * hi;
        sm.e.Ox[swave][srow][db * 32 + lh] = o_acc[db][r];
      }
    if (hi == 0) sm.e.Lx[swave][lh] = lt;
  }
  __syncthreads();
  if (thalf == 0) {
    lt += sm.e.Lx[swave][lh];
#pragma unroll
    for (int db = 0; db < 2; db++)
#pragma unroll
      for (int r = 0; r < 16; r++) {
        int srow = (r & 3) + 8 * (r >> 2) + 4 * hi;
        o_acc[db][r] += sm.e.Ox[swave][srow][db * 32 + lh];
      }
    sm.e.Ls[swave][lh] = 1.0f / lt;
    __builtin_amdgcn_wave_barrier();
    f32x4 inv[4];
#pragma unroll
    for (int a = 0; a < 4; a++) inv[a] = *(const f32x4*)&sm.e.Ls[swave][8 * a + 4 * hi];
#pragma unroll
    for (int db = 0; db < 2; db++) {
#pragma unroll
      for (int r = 0; r < 16; r++) {
        int srow = (r & 3) + 8 * (r >> 2) + 4 * hi;
        size_t o = (size_t)(b * 2048 + sBase + srow) * DM + qoff + db * 32 + lh;
        out[o] = f2bf(o_acc[db][r] * inv[r >> 2][r & 3]);
      }
    }
  }
}

extern "C" void kernel_launch(void* const* d_in, const int* in_sizes, int n_in,
                              void* d_out, int out_size, void* d_ws, size_t ws_size,
                              hipStream_t stream) {
  const float* q  = (const float*)d_in[0];
  const float* k  = (const float*)d_in[1];
  const float* v  = (const float*)d_in[2];
  const float* Wq = (const float*)d_in[3];
  const float* bq = (const float*)d_in[4];
  const float* Wk = (const float*)d_in[5];
  const float* bk = (const float*)d_in[6];
  const float* Wv = (const float*)d_in[7];
  const float* bv = (const float*)d_in[8];
  const float* Wo = (const float*)d_in[9];
  const float* bo = (const float*)d_in[10];

  u16* p = (u16*)d_ws;
  u16* WqkvT = p; p += (size_t)3072 * 2048;   // rows: 0-2047 Wq^T, 2048-2559 Wk^T, 2560-3071 Wv^T
  u16* WoT   = p; p += (size_t)2048 * 2048;
  u16* qb    = p; p += (size_t)4096 * 2048;   // bf16 casts of q/k/v; att aliases qb
  u16* kb    = p; p += (size_t)4096 * 2048;
  u16* vb    = p; p += (size_t)4096 * 2048;
  u16* qhb   = p; p += (size_t)4096 * 2048;
  u16* kvb   = p; p += (size_t)4096 * 1024;
  u16* vtb   = p; p += (size_t)16 * 64 * 2048;
  u16* att   = qb;  // reuse: qb dead after gemm_proj

  cast3<<<dim3(4096, 1, 3), 256, 0, stream>>>(q, k, v, qb, kb, vb);

  transpose_cast<<<dim3(32, 32), 256, 0, stream>>>(Wq, WqkvT, 2048, 2048);
  transpose_cast<<<dim3(8, 32), 256, 0, stream>>>(Wk, WqkvT + (size_t)2048 * 2048, 2048, 512);
  transpose_cast<<<dim3(8, 32), 256, 0, stream>>>(Wv, WqkvT + (size_t)2560 * 2048, 2048, 512);
  transpose_cast<<<dim3(32, 32), 256, 0, stream>>>(Wo, WoT, 2048, 2048);

  gemm_proj<<<dim3(24, 32), 256, 0, stream>>>(qb, kb, vb, WqkvT, bq, bk, bv, qhb, kvb, vtb);

  attn2<<<dim3(16, 64), 512, 0, stream>>>(qhb, kvb, vtb, att);

  gemm_o<<<dim3(16, 32), 256, 0, stream>>>(att, WoT, bo, (float*)d_out);
}

// Round 7
// 430.620 us; speedup vs baseline: 3.1060x; 1.2057x over previous
//
#include <hip/hip_runtime.h>

typedef unsigned short u16;
typedef unsigned int u32;
typedef __attribute__((ext_vector_type(8))) short bf16x8;
typedef __attribute__((ext_vector_type(4))) float f32x4;
typedef __attribute__((ext_vector_type(16))) float f32x16;

#define DM 2048
#define SQ_SCALE (0.125f * 1.44269504089f)

__device__ __forceinline__ u16 f2bf(float f) {
  union { float f; u32 u; } v; v.f = f;
  u32 r = v.u + 0x7fffu + ((v.u >> 16) & 1u);
  return (u16)(r >> 16);
}
// pack two floats to (bf16(hi)<<16)|bf16(lo), round-half-up
__device__ __forceinline__ u32 pkrn(float lo, float hi) {
  union { float f; u32 u; } a, b; a.f = lo; b.f = hi;
  return ((a.u + 0x8000u) >> 16) | ((b.u + 0x8000u) & 0xffff0000u);
}
// hw packed cvt: dst = {bf16(lo) in [15:0], bf16(hi) in [31:16]} (RNE)
__device__ __forceinline__ u32 cvtpk(float lo, float hi) {
  u32 r;
  asm("v_cvt_pk_bf16_f32 %0, %1, %2" : "=v"(r) : "v"(lo), "v"(hi));
  return r;
}
__device__ __forceinline__ void gload16(const u16* g, u16* l) {
  __builtin_amdgcn_global_load_lds((const __attribute__((address_space(1))) void*)g,
                                   (__attribute__((address_space(3))) void*)l, 16, 0, 0);
}

// fp32 -> bf16 elementwise, 8 elems/thread; z selects tensor
__global__ __launch_bounds__(256) void cast3(const float* __restrict__ a0,
                                             const float* __restrict__ a1,
                                             const float* __restrict__ a2,
                                             u16* __restrict__ o0,
                                             u16* __restrict__ o1,
                                             u16* __restrict__ o2) {
  const float* in; u16* out;
  if (blockIdx.z == 0) { in = a0; out = o0; }
  else if (blockIdx.z == 1) { in = a1; out = o1; }
  else { in = a2; out = o2; }
  size_t i = ((size_t)blockIdx.x * 256 + threadIdx.x) * 8;
  float4 f0 = *(const float4*)(in + i);
  float4 f1 = *(const float4*)(in + i + 4);
  uint4 w = {pkrn(f0.x, f0.y), pkrn(f0.z, f0.w), pkrn(f1.x, f1.y), pkrn(f1.z, f1.w)};
  *(uint4*)(out + i) = w;
}

// fp32 [K][N] -> bf16 [N][K], 64x64 tiles
__global__ __launch_bounds__(256) void transpose_cast(const float* __restrict__ in,
                                                      u16* __restrict__ out,
                                                      int K, int N) {
  __shared__ u16 s[64][72];
  int n0 = blockIdx.x * 64, k0 = blockIdx.y * 64;
  int t = threadIdx.x;
  int r = t >> 2;
  int cc = (t & 3) * 16;
  const float* ip = in + (size_t)(k0 + r) * N + n0 + cc;
  u16 tmp[16];
#pragma unroll
  for (int i = 0; i < 16; i += 4) {
    float4 v = *(const float4*)(ip + i);
    tmp[i] = f2bf(v.x); tmp[i + 1] = f2bf(v.y);
    tmp[i + 2] = f2bf(v.z); tmp[i + 3] = f2bf(v.w);
  }
  *(uint4*)&s[r][cc] = *(uint4*)tmp;
  *(uint4*)&s[r][cc + 8] = *(uint4*)(tmp + 8);
  __syncthreads();
#pragma unroll
  for (int i = 0; i < 16; i++) tmp[i] = s[cc + i][r];
  u16* op = out + (size_t)(n0 + r) * K + k0 + cc;
  *(uint4*)op = *(uint4*)tmp;
  *(uint4*)(op + 8) = *(uint4*)(tmp + 8);
}

// Fused QKV projection: C = A @ Bt^T + bias. A selected by n-tile.
// N logical 3072: [0,2048) Q -> qhb (scaled), [2048,2560) K -> kvb cols 0-511,
// [2560,3072) V -> V^T written DIRECTLY to vtb[(b*8+g)*64+d][t] (transpose_v fused).
__global__ __launch_bounds__(256) void gemm_proj(const u16* __restrict__ qb,
                                                 const u16* __restrict__ kb,
                                                 const u16* __restrict__ vb,
                                                 const u16* __restrict__ Bt,
                                                 const float* __restrict__ bqp,
                                                 const float* __restrict__ bkp,
                                                 const float* __restrict__ bvp,
                                                 u16* __restrict__ qhb,
                                                 u16* __restrict__ kvb,
                                                 u16* __restrict__ vtb) {
  __shared__ u16 As[128 * 32];
  __shared__ u16 Bs[128 * 32];
  int n0 = blockIdx.x * 128, m0 = blockIdx.y * 128;
  const u16* A; const float* bias; u16* C; int cw, bofs; float esc;
  if (n0 < 2048)      { A = qb; bias = bqp; C = qhb; cw = 2048; bofs = 0;    esc = SQ_SCALE; }
  else if (n0 < 2560) { A = kb; bias = bkp; C = kvb; cw = 1024; bofs = 2048; esc = 1.0f; }
  else                { A = vb; bias = bvp; C = kvb; cw = 1024; bofs = 2560; esc = 1.0f; }
  int ccol0 = (n0 < 2048) ? n0 : (n0 - 2048);

  int tid = threadIdx.x, wave = tid >> 6, lane = tid & 63;
  int lq = lane & 15, quad = lane >> 4;
  int wm = (wave & 1) * 64, wn = (wave >> 1) * 64;

  f32x4 zero = {0.f, 0.f, 0.f, 0.f};
  f32x4 acc[4][4];
#pragma unroll
  for (int i = 0; i < 4; i++)
#pragma unroll
    for (int j = 0; j < 4; j++) acc[i][j] = zero;

  const u16* gA = A + (size_t)(m0 + wave * 16 + (lane >> 2)) * 2048 + (lane & 3) * 8;
  const u16* gB = Bt + (size_t)(n0 + wave * 16 + (lane >> 2)) * 2048 + (lane & 3) * 8;
  u16* lA0 = &As[(wave * 16) * 32];
  u16* lA1 = &As[(64 + wave * 16) * 32];
  u16* lB0 = &Bs[(wave * 16) * 32];
  u16* lB1 = &Bs[(64 + wave * 16) * 32];

  for (int k0 = 0; k0 < 2048; k0 += 32) {
    __syncthreads();
    gload16(gA + k0, lA0);
    gload16(gA + (size_t)64 * 2048 + k0, lA1);
    gload16(gB + k0, lB0);
    gload16(gB + (size_t)64 * 2048 + k0, lB1);
    __syncthreads();
    bf16x8 af[4], bf[4];
#pragma unroll
    for (int i = 0; i < 4; i++) af[i] = *(const bf16x8*)&As[(wm + i * 16 + lq) * 32 + quad * 8];
#pragma unroll
    for (int j = 0; j < 4; j++) bf[j] = *(const bf16x8*)&Bs[(wn + j * 16 + lq) * 32 + quad * 8];
#pragma unroll
    for (int i = 0; i < 4; i++)
#pragma unroll
      for (int j = 0; j < 4; j++)
        acc[i][j] = __builtin_amdgcn_mfma_f32_16x16x32_bf16(af[i], bf[j], acc[i][j], 0, 0, 0);
  }
  if (n0 >= 2560) {
    // V: write V^T directly. col cv in [0,512) = g*64+d; rows are t.
    // rg 0..3 -> consecutive t -> 8B contiguous stores (t%4==0 -> 8B aligned).
#pragma unroll
    for (int j = 0; j < 4; j++) {
      int cv = (n0 - 2560) + wn + j * 16 + lq;
      float bvv = bias[cv];
      u16* vout = vtb + (size_t)cv * 2048;
#pragma unroll
      for (int i = 0; i < 4; i++) {
        int row = m0 + wm + i * 16 + quad * 4;
        int bb = row >> 11, tt = row & 2047;
        u16 w4[4];
#pragma unroll
        for (int rg = 0; rg < 4; rg++) w4[rg] = f2bf(acc[i][j][rg] + bvv);
        *(uint2*)(vout + (size_t)bb * 8 * 64 * 2048 + tt) = *(uint2*)w4;
      }
    }
  } else {
#pragma unroll
    for (int j = 0; j < 4; j++) {
      int nglob = n0 + wn + j * 16 + lq;
      float bv = bias[nglob - bofs];
      int col = ccol0 + wn + j * 16 + lq;
#pragma unroll
      for (int i = 0; i < 4; i++) {
#pragma unroll
        for (int rg = 0; rg < 4; rg++) {
          int row = m0 + wm + i * 16 + quad * 4 + rg;
          C[(size_t)row * cw + col] = f2bf((acc[i][j][rg] + bv) * esc);
        }
      }
    }
  }
}

// O projection: fp32 C out
__global__ __launch_bounds__(256) void gemm_o(const u16* __restrict__ A,
                                              const u16* __restrict__ Bt,
                                              const float* __restrict__ bias,
                                              float* __restrict__ C) {
  __shared__ u16 As[128 * 32];
  __shared__ u16 Bs[128 * 32];
  int n0 = blockIdx.x * 128, m0 = blockIdx.y * 128;
  int tid = threadIdx.x, wave = tid >> 6, lane = tid & 63;
  int lq = lane & 15, quad = lane >> 4;
  int wm = (wave & 1) * 64, wn = (wave >> 1) * 64;

  f32x4 zero = {0.f, 0.f, 0.f, 0.f};
  f32x4 acc[4][4];
#pragma unroll
  for (int i = 0; i < 4; i++)
#pragma unroll
    for (int j = 0; j < 4; j++) acc[i][j] = zero;

  const u16* gA = A + (size_t)(m0 + wave * 16 + (lane >> 2)) * 2048 + (lane & 3) * 8;
  const u16* gB = Bt + (size_t)(n0 + wave * 16 + (lane >> 2)) * 2048 + (lane & 3) * 8;
  u16* lA0 = &As[(wave * 16) * 32];
  u16* lA1 = &As[(64 + wave * 16) * 32];
  u16* lB0 = &Bs[(wave * 16) * 32];
  u16* lB1 = &Bs[(64 + wave * 16) * 32];

  for (int k0 = 0; k0 < 2048; k0 += 32) {
    __syncthreads();
    gload16(gA + k0, lA0);
    gload16(gA + (size_t)64 * 2048 + k0, lA1);
    gload16(gB + k0, lB0);
    gload16(gB + (size_t)64 * 2048 + k0, lB1);
    __syncthreads();
    bf16x8 af[4], bf[4];
#pragma unroll
    for (int i = 0; i < 4; i++) af[i] = *(const bf16x8*)&As[(wm + i * 16 + lq) * 32 + quad * 8];
#pragma unroll
    for (int j = 0; j < 4; j++) bf[j] = *(const bf16x8*)&Bs[(wn + j * 16 + lq) * 32 + quad * 8];
#pragma unroll
    for (int i = 0; i < 4; i++)
#pragma unroll
      for (int j = 0; j < 4; j++)
        acc[i][j] = __builtin_amdgcn_mfma_f32_16x16x32_bf16(af[i], bf[j], acc[i][j], 0, 0, 0);
  }
#pragma unroll
  for (int j = 0; j < 4; j++) {
    int col = n0 + wn + j * 16 + lq;
    float bv = bias[col];
#pragma unroll
    for (int i = 0; i < 4; i++) {
#pragma unroll
      for (int rg = 0; rg < 4; rg++) {
        int row = m0 + wm + i * 16 + quad * 4 + rg;
        C[(size_t)row * 2048 + col] = acc[i][j][rg] + bv;
      }
    }
  }
}

// Flash attention v7 = R3 structure (256 thr, 4 waves x 32 s-rows, known 104us)
// + double-buffered K/V LDS: ONE barrier per t-iter instead of two.
// Correctness: buf[c] rewritten at iter t+2; sync(t+1) full-drains LDS ops of
// all waves' compute(t) reads (__syncthreads waits lgkmcnt) -> no WAR hazard.
// R6's 512-thr 2-T-half variant is reverted: 30x bank conflicts, 2x slower.
__global__ __launch_bounds__(256) void attn2(const u16* __restrict__ qh,
                                             const u16* __restrict__ kvb,
                                             const u16* __restrict__ vtb,
                                             u16* __restrict__ out) {
  __shared__ u16 Ks[2][32][72];   // [buf][t][d] 144B rows
  __shared__ u16 Vs[2][64][40];   // [buf][d][t] 80B rows
  __shared__ float Ls[4][32];
  int flat = blockIdx.x + (blockIdx.y << 4);
  int w = ((flat & 7) << 7) + (flat >> 3);   // bijective: 1024 blocks, 128/XCD
  int head = w >> 4;
  int b = head >> 5, g = (head >> 2) & 7, h = head & 3;
  int tid = threadIdx.x, wave = tid >> 6, lane = tid & 63;
  int lh = lane & 31, hi = lane >> 5;
  const int qoff = (g * 4 + h) * 64;
  const int koff = g * 64;
  int sBase = (w & 15) * 128 + wave * 32;

  // Q as B-operand (Q^T): lane n=s=lh, k=d = st*16 + hi*8 + j
  bf16x8 qf[4];
#pragma unroll
  for (int st = 0; st < 4; st++)
    qf[st] = *(const bf16x8*)(qh + (size_t)(b * 2048 + sBase + lh) * DM +
                              qoff + st * 16 + hi * 8);

  f32x16 o_acc[2];
#pragma unroll
  for (int db = 0; db < 2; db++)
#pragma unroll
    for (int r = 0; r < 16; r++) o_acc[db][r] = 0.f;
  float l_acc = 0.f;

  int sr = tid >> 3, sc = (tid & 7) * 8;  // K staging
  int vd = tid >> 2, vc = (tid & 3) * 8;  // V^T staging
  const u16* kbase = kvb + (size_t)b * 2048 * 1024 + koff;
  const u16* vbase = vtb + (size_t)(head >> 2) * 64 * 2048 + (size_t)vd * 2048;

  uint4 kreg = *(const uint4*)(kbase + (size_t)sr * 1024 + sc);
  uint4 vreg = *(const uint4*)(vbase + vc);

  int c = 0;
  for (int t0 = 0; t0 < 2048; t0 += 32) {
    // write current tile to buf[c], issue prefetch of next tile, ONE sync
    *(uint4*)&Ks[c][sr][sc] = kreg;
    *(uint4*)&Vs[c][vd][vc] = vreg;
    int tn = (t0 + 32 < 2048) ? t0 + 32 : 0;
    kreg = *(const uint4*)(kbase + (size_t)(tn + sr) * 1024 + sc);
    vreg = *(const uint4*)(vbase + tn + vc);
    __syncthreads();

    bf16x8 kf[4], vf[2][2];
#pragma unroll
    for (int st = 0; st < 4; st++) kf[st] = *(const bf16x8*)&Ks[c][lh][st * 16 + hi * 8];
#pragma unroll
    for (int T = 0; T < 2; T++)
#pragma unroll
      for (int db = 0; db < 2; db++)
        vf[T][db] = *(const bf16x8*)&Vs[c][db * 32 + lh][T * 16 + hi * 8];

    f32x16 st_acc;
#pragma unroll
    for (int r = 0; r < 16; r++) st_acc[r] = 0.f;
    __builtin_amdgcn_s_setprio(1);
#pragma unroll
    for (int st = 0; st < 4; st++)
      st_acc = __builtin_amdgcn_mfma_f32_32x32x16_bf16(kf[st], qf[st], st_acc, 0, 0, 0);
    __builtin_amdgcn_s_setprio(0);
    // S^T: lane holds col s=lh, rows t=(r&3)+8*(r>>2)+4*hi
    float pr[16];
#pragma unroll
    for (int r = 0; r < 16; r++) pr[r] = __builtin_amdgcn_exp2f(st_acc[r]);
    float s0 = ((pr[0] + pr[1]) + (pr[2] + pr[3])) + ((pr[4] + pr[5]) + (pr[6] + pr[7]));
    float s1 = ((pr[8] + pr[9]) + (pr[10] + pr[11])) + ((pr[12] + pr[13]) + (pr[14] + pr[15]));
    l_acc += s0 + s1;
    u32 pk[8];
#pragma unroll
    for (int a = 0; a < 4; a++) {
      pk[2 * a] = cvtpk(pr[4 * a], pr[4 * a + 1]);
      pk[2 * a + 1] = cvtpk(pr[4 * a + 2], pr[4 * a + 3]);
    }
#pragma unroll
    for (int T = 0; T < 2; T++) {
      // A-operand for PV needs t = 16T + 8*hi + j; exchange halves via xor-32
      u32 E0 = hi ? pk[4 * T] : pk[4 * T + 2];
      u32 E1 = hi ? pk[4 * T + 1] : pk[4 * T + 3];
      u32 X0 = __shfl_xor(E0, 32);
      u32 X1 = __shfl_xor(E1, 32);
      union { u32 u[4]; bf16x8 v; } af;
      af.u[0] = hi ? X0 : pk[4 * T];
      af.u[1] = hi ? X1 : pk[4 * T + 1];
      af.u[2] = hi ? pk[4 * T + 2] : X0;
      af.u[3] = hi ? pk[4 * T + 3] : X1;
      __builtin_amdgcn_s_setprio(1);
#pragma unroll
      for (int db = 0; db < 2; db++)
        o_acc[db] = __builtin_amdgcn_mfma_f32_32x32x16_bf16(af.v, vf[T][db], o_acc[db], 0, 0, 0);
      __builtin_amdgcn_s_setprio(0);
    }
    c ^= 1;
  }

  // epilogue: l broadcast via LDS, normalize, store
  {
    float lt = l_acc + __shfl_xor(l_acc, 32);
    Ls[wave][lh] = 1.0f / lt;
  }
  __builtin_amdgcn_wave_barrier();
  {
    f32x4 inv[4];
#pragma unroll
    for (int a = 0; a < 4; a++) inv[a] = *(const f32x4*)&Ls[wave][8 * a + 4 * hi];
#pragma unroll
    for (int db = 0; db < 2; db++) {
#pragma unroll
      for (int r = 0; r < 16; r++) {
        int srow = (r & 3) + 8 * (r >> 2) + 4 * hi;
        size_t o = (size_t)(b * 2048 + sBase + srow) * DM + qoff + db * 32 + lh;
        out[o] = f2bf(o_acc[db][r] * inv[r >> 2][r & 3]);
      }
    }
  }
}

extern "C" void kernel_launch(void* const* d_in, const int* in_sizes, int n_in,
                              void* d_out, int out_size, void* d_ws, size_t ws_size,
                              hipStream_t stream) {
  const float* q  = (const float*)d_in[0];
  const float* k  = (const float*)d_in[1];
  const float* v  = (const float*)d_in[2];
  const float* Wq = (const float*)d_in[3];
  const float* bq = (const float*)d_in[4];
  const float* Wk = (const float*)d_in[5];
  const float* bk = (const float*)d_in[6];
  const float* Wv = (const float*)d_in[7];
  const float* bv = (const float*)d_in[8];
  const float* Wo = (const float*)d_in[9];
  const float* bo = (const float*)d_in[10];

  u16* p = (u16*)d_ws;
  u16* WqkvT = p; p += (size_t)3072 * 2048;   // rows: 0-2047 Wq^T, 2048-2559 Wk^T, 2560-3071 Wv^T
  u16* WoT   = p; p += (size_t)2048 * 2048;
  u16* qb    = p; p += (size_t)4096 * 2048;   // bf16 casts of q/k/v; att aliases qb
  u16* kb    = p; p += (size_t)4096 * 2048;
  u16* vb    = p; p += (size_t)4096 * 2048;
  u16* qhb   = p; p += (size_t)4096 * 2048;
  u16* kvb   = p; p += (size_t)4096 * 1024;
  u16* vtb   = p; p += (size_t)16 * 64 * 2048;
  u16* att   = qb;  // reuse: qb dead after gemm_proj

  cast3<<<dim3(4096, 1, 3), 256, 0, stream>>>(q, k, v, qb, kb, vb);

  transpose_cast<<<dim3(32, 32), 256, 0, stream>>>(Wq, WqkvT, 2048, 2048);
  transpose_cast<<<dim3(8, 32), 256, 0, stream>>>(Wk, WqkvT + (size_t)2048 * 2048, 2048, 512);
  transpose_cast<<<dim3(8, 32), 256, 0, stream>>>(Wv, WqkvT + (size_t)2560 * 2048, 2048, 512);
  transpose_cast<<<dim3(32, 32), 256, 0, stream>>>(Wo, WoT, 2048, 2048);

  gemm_proj<<<dim3(24, 32), 256, 0, stream>>>(qb, kb, vb, WqkvT, bq, bk, bv, qhb, kvb, vtb);

  attn2<<<dim3(16, 64), 256, 0, stream>>>(qhb, kvb, vtb, att);

  gemm_o<<<dim3(16, 32), 256, 0, stream>>>(att, WoT, bo, (float*)d_out);
}

// Round 8
// 410.516 us; speedup vs baseline: 3.2581x; 1.0490x over previous
//
#include <hip/hip_runtime.h>

typedef unsigned short u16;
typedef unsigned int u32;
typedef __attribute__((ext_vector_type(8))) short bf16x8;
typedef __attribute__((ext_vector_type(4))) float f32x4;
typedef __attribute__((ext_vector_type(16))) float f32x16;

#define DM 2048
#define SQ_SCALE (0.125f * 1.44269504089f)

__device__ __forceinline__ u16 f2bf(float f) {
  union { float f; u32 u; } v; v.f = f;
  u32 r = v.u + 0x7fffu + ((v.u >> 16) & 1u);
  return (u16)(r >> 16);
}
// pack two floats to (bf16(hi)<<16)|bf16(lo), round-half-up
__device__ __forceinline__ u32 pkrn(float lo, float hi) {
  union { float f; u32 u; } a, b; a.f = lo; b.f = hi;
  return ((a.u + 0x8000u) >> 16) | ((b.u + 0x8000u) & 0xffff0000u);
}
// hw packed cvt: dst = {bf16(lo) in [15:0], bf16(hi) in [31:16]} (RNE)
__device__ __forceinline__ u32 cvtpk(float lo, float hi) {
  u32 r;
  asm("v_cvt_pk_bf16_f32 %0, %1, %2" : "=v"(r) : "v"(lo), "v"(hi));
  return r;
}
__device__ __forceinline__ void gload16(const u16* g, u16* l) {
  __builtin_amdgcn_global_load_lds((const __attribute__((address_space(1))) void*)g,
                                   (__attribute__((address_space(3))) void*)l, 16, 0, 0);
}

// Merged preprocessing: one launch.
// blocks [0,12288): fp32->bf16 cast of q/k/v (4096 blocks each)
// blocks [12288,14848): W transposes -> bf16 [N][K] (Wq 1024, Wk 256, Wv 256, Wo 1024)
__global__ __launch_bounds__(256) void prep(const float* __restrict__ q,
                                            const float* __restrict__ k,
                                            const float* __restrict__ v,
                                            const float* __restrict__ Wq,
                                            const float* __restrict__ Wk,
                                            const float* __restrict__ Wv,
                                            const float* __restrict__ Wo,
                                            u16* __restrict__ qb,
                                            u16* __restrict__ kb,
                                            u16* __restrict__ vb,
                                            u16* __restrict__ WqkvT,
                                            u16* __restrict__ WoT) {
  __shared__ u16 s[64][72];
  int bid = blockIdx.x;
  if (bid < 12288) {
    int z = bid >> 12, x = bid & 4095;
    const float* in = (z == 0) ? q : (z == 1) ? k : v;
    u16* out = (z == 0) ? qb : (z == 1) ? kb : vb;
    size_t i = ((size_t)x * 256 + threadIdx.x) * 8;
    float4 f0 = *(const float4*)(in + i);
    float4 f1 = *(const float4*)(in + i + 4);
    uint4 w = {pkrn(f0.x, f0.y), pkrn(f0.z, f0.w), pkrn(f1.x, f1.y), pkrn(f1.z, f1.w)};
    *(uint4*)(out + i) = w;
    return;
  }
  int off = bid - 12288;
  const float* in; u16* out; int K, N, bx, by;
  if (off < 1024)      { in = Wq; out = WqkvT;                          K = 2048; N = 2048; bx = off & 31; by = off >> 5; }
  else if (off < 1280) { int i2 = off - 1024; in = Wk; out = WqkvT + (size_t)2048 * 2048; K = 2048; N = 512; bx = i2 & 7; by = i2 >> 3; }
  else if (off < 1536) { int i2 = off - 1280; in = Wv; out = WqkvT + (size_t)2560 * 2048; K = 2048; N = 512; bx = i2 & 7; by = i2 >> 3; }
  else                 { int i2 = off - 1536; in = Wo; out = WoT;       K = 2048; N = 2048; bx = i2 & 31; by = i2 >> 5; }
  int n0 = bx * 64, k0 = by * 64;
  int t = threadIdx.x;
  int r = t >> 2;
  int cc = (t & 3) * 16;
  const float* ip = in + (size_t)(k0 + r) * N + n0 + cc;
  u16 tmp[16];
#pragma unroll
  for (int i = 0; i < 16; i += 4) {
    float4 vv = *(const float4*)(ip + i);
    tmp[i] = f2bf(vv.x); tmp[i + 1] = f2bf(vv.y);
    tmp[i + 2] = f2bf(vv.z); tmp[i + 3] = f2bf(vv.w);
  }
  *(uint4*)&s[r][cc] = *(uint4*)tmp;
  *(uint4*)&s[r][cc + 8] = *(uint4*)(tmp + 8);
  __syncthreads();
#pragma unroll
  for (int i = 0; i < 16; i++) tmp[i] = s[cc + i][r];
  u16* op = out + (size_t)(n0 + r) * K + k0 + cc;
  *(uint4*)op = *(uint4*)tmp;
  *(uint4*)(op + 8) = *(uint4*)(tmp + 8);
}

// Fused QKV projection, BK=64 (two 32-col LDS buffers per operand; read pattern
// identical to validated BK=32 -> same bank behavior; barriers per FLOP halved).
// N logical 3072: [0,2048) Q -> qhb (scaled), [2048,2560) K -> kvb,
// [2560,3072) V -> V^T directly to vtb[(b*8+g)*64+d][t] (transpose fused).
__global__ __launch_bounds__(256) void gemm_proj(const u16* __restrict__ qb,
                                                 const u16* __restrict__ kb,
                                                 const u16* __restrict__ vb,
                                                 const u16* __restrict__ Bt,
                                                 const float* __restrict__ bqp,
                                                 const float* __restrict__ bkp,
                                                 const float* __restrict__ bvp,
                                                 u16* __restrict__ qhb,
                                                 u16* __restrict__ kvb,
                                                 u16* __restrict__ vtb) {
  __shared__ u16 As[2][128 * 32];
  __shared__ u16 Bs[2][128 * 32];
  int n0 = blockIdx.x * 128, m0 = blockIdx.y * 128;
  const u16* A; const float* bias; u16* C; int cw, bofs; float esc;
  if (n0 < 2048)      { A = qb; bias = bqp; C = qhb; cw = 2048; bofs = 0;    esc = SQ_SCALE; }
  else if (n0 < 2560) { A = kb; bias = bkp; C = kvb; cw = 1024; bofs = 2048; esc = 1.0f; }
  else                { A = vb; bias = bvp; C = kvb; cw = 1024; bofs = 2560; esc = 1.0f; }
  int ccol0 = (n0 < 2048) ? n0 : (n0 - 2048);

  int tid = threadIdx.x, wave = tid >> 6, lane = tid & 63;
  int lq = lane & 15, quad = lane >> 4;
  int wm = (wave & 1) * 64, wn = (wave >> 1) * 64;

  f32x4 zero = {0.f, 0.f, 0.f, 0.f};
  f32x4 acc[4][4];
#pragma unroll
  for (int i = 0; i < 4; i++)
#pragma unroll
    for (int j = 0; j < 4; j++) acc[i][j] = zero;

  const u16* gA = A + (size_t)(m0 + wave * 16 + (lane >> 2)) * 2048 + (lane & 3) * 8;
  const u16* gB = Bt + (size_t)(n0 + wave * 16 + (lane >> 2)) * 2048 + (lane & 3) * 8;
  u16* lA0[2] = {&As[0][(wave * 16) * 32], &As[1][(wave * 16) * 32]};
  u16* lA1[2] = {&As[0][(64 + wave * 16) * 32], &As[1][(64 + wave * 16) * 32]};
  u16* lB0[2] = {&Bs[0][(wave * 16) * 32], &Bs[1][(wave * 16) * 32]};
  u16* lB1[2] = {&Bs[0][(64 + wave * 16) * 32], &Bs[1][(64 + wave * 16) * 32]};

  for (int k0 = 0; k0 < 2048; k0 += 64) {
    __syncthreads();
    gload16(gA + k0, lA0[0]);
    gload16(gA + (size_t)64 * 2048 + k0, lA1[0]);
    gload16(gA + k0 + 32, lA0[1]);
    gload16(gA + (size_t)64 * 2048 + k0 + 32, lA1[1]);
    gload16(gB + k0, lB0[0]);
    gload16(gB + (size_t)64 * 2048 + k0, lB1[0]);
    gload16(gB + k0 + 32, lB0[1]);
    gload16(gB + (size_t)64 * 2048 + k0 + 32, lB1[1]);
    __syncthreads();
#pragma unroll
    for (int hf = 0; hf < 2; hf++) {
      bf16x8 af[4], bf[4];
#pragma unroll
      for (int i = 0; i < 4; i++) af[i] = *(const bf16x8*)&As[hf][(wm + i * 16 + lq) * 32 + quad * 8];
#pragma unroll
      for (int j = 0; j < 4; j++) bf[j] = *(const bf16x8*)&Bs[hf][(wn + j * 16 + lq) * 32 + quad * 8];
#pragma unroll
      for (int i = 0; i < 4; i++)
#pragma unroll
        for (int j = 0; j < 4; j++)
          acc[i][j] = __builtin_amdgcn_mfma_f32_16x16x32_bf16(af[i], bf[j], acc[i][j], 0, 0, 0);
    }
  }
  if (n0 >= 2560) {
    // V: write V^T directly. col cv in [0,512) = g*64+d; rows are t.
#pragma unroll
    for (int j = 0; j < 4; j++) {
      int cv = (n0 - 2560) + wn + j * 16 + lq;
      float bvv = bias[cv];
      u16* vout = vtb + (size_t)cv * 2048;
#pragma unroll
      for (int i = 0; i < 4; i++) {
        int row = m0 + wm + i * 16 + quad * 4;
        int bb = row >> 11, tt = row & 2047;
        u16 w4[4];
#pragma unroll
        for (int rg = 0; rg < 4; rg++) w4[rg] = f2bf(acc[i][j][rg] + bvv);
        *(uint2*)(vout + (size_t)bb * 8 * 64 * 2048 + tt) = *(uint2*)w4;
      }
    }
  } else {
#pragma unroll
    for (int j = 0; j < 4; j++) {
      int nglob = n0 + wn + j * 16 + lq;
      float bv = bias[nglob - bofs];
      int col = ccol0 + wn + j * 16 + lq;
#pragma unroll
      for (int i = 0; i < 4; i++) {
#pragma unroll
        for (int rg = 0; rg < 4; rg++) {
          int row = m0 + wm + i * 16 + quad * 4 + rg;
          C[(size_t)row * cw + col] = f2bf((acc[i][j][rg] + bv) * esc);
        }
      }
    }
  }
}

// O projection: fp32 C out, BK=64 two-buffer (same scheme as gemm_proj)
__global__ __launch_bounds__(256) void gemm_o(const u16* __restrict__ A,
                                              const u16* __restrict__ Bt,
                                              const float* __restrict__ bias,
                                              float* __restrict__ C) {
  __shared__ u16 As[2][128 * 32];
  __shared__ u16 Bs[2][128 * 32];
  int n0 = blockIdx.x * 128, m0 = blockIdx.y * 128;
  int tid = threadIdx.x, wave = tid >> 6, lane = tid & 63;
  int lq = lane & 15, quad = lane >> 4;
  int wm = (wave & 1) * 64, wn = (wave >> 1) * 64;

  f32x4 zero = {0.f, 0.f, 0.f, 0.f};
  f32x4 acc[4][4];
#pragma unroll
  for (int i = 0; i < 4; i++)
#pragma unroll
    for (int j = 0; j < 4; j++) acc[i][j] = zero;

  const u16* gA = A + (size_t)(m0 + wave * 16 + (lane >> 2)) * 2048 + (lane & 3) * 8;
  const u16* gB = Bt + (size_t)(n0 + wave * 16 + (lane >> 2)) * 2048 + (lane & 3) * 8;
  u16* lA0[2] = {&As[0][(wave * 16) * 32], &As[1][(wave * 16) * 32]};
  u16* lA1[2] = {&As[0][(64 + wave * 16) * 32], &As[1][(64 + wave * 16) * 32]};
  u16* lB0[2] = {&Bs[0][(wave * 16) * 32], &Bs[1][(wave * 16) * 32]};
  u16* lB1[2] = {&Bs[0][(64 + wave * 16) * 32], &Bs[1][(64 + wave * 16) * 32]};

  for (int k0 = 0; k0 < 2048; k0 += 64) {
    __syncthreads();
    gload16(gA + k0, lA0[0]);
    gload16(gA + (size_t)64 * 2048 + k0, lA1[0]);
    gload16(gA + k0 + 32, lA0[1]);
    gload16(gA + (size_t)64 * 2048 + k0 + 32, lA1[1]);
    gload16(gB + k0, lB0[0]);
    gload16(gB + (size_t)64 * 2048 + k0, lB1[0]);
    gload16(gB + k0 + 32, lB0[1]);
    gload16(gB + (size_t)64 * 2048 + k0 + 32, lB1[1]);
    __syncthreads();
#pragma unroll
    for (int hf = 0; hf < 2; hf++) {
      bf16x8 af[4], bf[4];
#pragma unroll
      for (int i = 0; i < 4; i++) af[i] = *(const bf16x8*)&As[hf][(wm + i * 16 + lq) * 32 + quad * 8];
#pragma unroll
      for (int j = 0; j < 4; j++) bf[j] = *(const bf16x8*)&Bs[hf][(wn + j * 16 + lq) * 32 + quad * 8];
#pragma unroll
      for (int i = 0; i < 4; i++)
#pragma unroll
        for (int j = 0; j < 4; j++)
          acc[i][j] = __builtin_amdgcn_mfma_f32_16x16x32_bf16(af[i], bf[j], acc[i][j], 0, 0, 0);
    }
  }
#pragma unroll
  for (int j = 0; j < 4; j++) {
    int col = n0 + wn + j * 16 + lq;
    float bv = bias[col];
#pragma unroll
    for (int i = 0; i < 4; i++) {
#pragma unroll
      for (int rg = 0; rg < 4; rg++) {
        int row = m0 + wm + i * 16 + quad * 4 + rg;
        C[(size_t)row * 2048 + col] = acc[i][j][rg] + bv;
      }
    }
  }
}

// Flash attention v8 = R3 structure (256 thr, 4 waves x 32 s-rows) + dbuf LDS
// with ONE barrier/iter and prefetch issued AFTER the barrier (R7 issued it
// before -> compiler's vmcnt(0) drain at s_barrier exposed full load latency
// per iter, 104->115us). Now: write buf[c] (waits kreg), barrier, issue next
// loads, compute buf[c] -- load latency hides under compute, consumed at next
// iter's write which precedes the next barrier.
__global__ __launch_bounds__(256) void attn2(const u16* __restrict__ qh,
                                             const u16* __restrict__ kvb,
                                             const u16* __restrict__ vtb,
                                             u16* __restrict__ out) {
  __shared__ u16 Ks[2][32][72];   // [buf][t][d] 144B rows
  __shared__ u16 Vs[2][64][40];   // [buf][d][t] 80B rows
  __shared__ float Ls[4][32];
  int flat = blockIdx.x + (blockIdx.y << 4);
  int w = ((flat & 7) << 7) + (flat >> 3);   // bijective: 1024 blocks, 128/XCD
  int head = w >> 4;
  int b = head >> 5, g = (head >> 2) & 7, h = head & 3;
  int tid = threadIdx.x, wave = tid >> 6, lane = tid & 63;
  int lh = lane & 31, hi = lane >> 5;
  const int qoff = (g * 4 + h) * 64;
  const int koff = g * 64;
  int sBase = (w & 15) * 128 + wave * 32;

  // Q as B-operand (Q^T): lane n=s=lh, k=d = st*16 + hi*8 + j
  bf16x8 qf[4];
#pragma unroll
  for (int st = 0; st < 4; st++)
    qf[st] = *(const bf16x8*)(qh + (size_t)(b * 2048 + sBase + lh) * DM +
                              qoff + st * 16 + hi * 8);

  f32x16 o_acc[2];
#pragma unroll
  for (int db = 0; db < 2; db++)
#pragma unroll
    for (int r = 0; r < 16; r++) o_acc[db][r] = 0.f;
  float l_acc = 0.f;

  int sr = tid >> 3, sc = (tid & 7) * 8;  // K staging
  int vd = tid >> 2, vc = (tid & 3) * 8;  // V^T staging
  const u16* kbase = kvb + (size_t)b * 2048 * 1024 + koff;
  const u16* vbase = vtb + (size_t)(head >> 2) * 64 * 2048 + (size_t)vd * 2048;

  uint4 kreg = *(const uint4*)(kbase + (size_t)sr * 1024 + sc);
  uint4 vreg = *(const uint4*)(vbase + vc);

  int c = 0;
  for (int t0 = 0; t0 < 2048; t0 += 32) {
    *(uint4*)&Ks[c][sr][sc] = kreg;
    *(uint4*)&Vs[c][vd][vc] = vreg;
    __syncthreads();
    // prefetch next tile AFTER the barrier: latency overlaps compute below
    int tn = (t0 + 32 < 2048) ? t0 + 32 : 0;
    kreg = *(const uint4*)(kbase + (size_t)(tn + sr) * 1024 + sc);
    vreg = *(const uint4*)(vbase + tn + vc);

    bf16x8 kf[4], vf[2][2];
#pragma unroll
    for (int st = 0; st < 4; st++) kf[st] = *(const bf16x8*)&Ks[c][lh][st * 16 + hi * 8];
#pragma unroll
    for (int T = 0; T < 2; T++)
#pragma unroll
      for (int db = 0; db < 2; db++)
        vf[T][db] = *(const bf16x8*)&Vs[c][db * 32 + lh][T * 16 + hi * 8];

    f32x16 st_acc;
#pragma unroll
    for (int r = 0; r < 16; r++) st_acc[r] = 0.f;
    __builtin_amdgcn_s_setprio(1);
#pragma unroll
    for (int st = 0; st < 4; st++)
      st_acc = __builtin_amdgcn_mfma_f32_32x32x16_bf16(kf[st], qf[st], st_acc, 0, 0, 0);
    __builtin_amdgcn_s_setprio(0);
    // S^T: lane holds col s=lh, rows t=(r&3)+8*(r>>2)+4*hi
    float pr[16];
#pragma unroll
    for (int r = 0; r < 16; r++) pr[r] = __builtin_amdgcn_exp2f(st_acc[r]);
    float s0 = ((pr[0] + pr[1]) + (pr[2] + pr[3])) + ((pr[4] + pr[5]) + (pr[6] + pr[7]));
    float s1 = ((pr[8] + pr[9]) + (pr[10] + pr[11])) + ((pr[12] + pr[13]) + (pr[14] + pr[15]));
    l_acc += s0 + s1;
    u32 pk[8];
#pragma unroll
    for (int a = 0; a < 4; a++) {
      pk[2 * a] = cvtpk(pr[4 * a], pr[4 * a + 1]);
      pk[2 * a + 1] = cvtpk(pr[4 * a + 2], pr[4 * a + 3]);
    }
#pragma unroll
    for (int T = 0; T < 2; T++) {
      // A-operand for PV needs t = 16T + 8*hi + j; exchange halves via xor-32
      u32 E0 = hi ? pk[4 * T] : pk[4 * T + 2];
      u32 E1 = hi ? pk[4 * T + 1] : pk[4 * T + 3];
      u32 X0 = __shfl_xor(E0, 32);
      u32 X1 = __shfl_xor(E1, 32);
      union { u32 u[4]; bf16x8 v; } af;
      af.u[0] = hi ? X0 : pk[4 * T];
      af.u[1] = hi ? X1 : pk[4 * T + 1];
      af.u[2] = hi ? pk[4 * T + 2] : X0;
      af.u[3] = hi ? pk[4 * T + 3] : X1;
      __builtin_amdgcn_s_setprio(1);
#pragma unroll
      for (int db = 0; db < 2; db++)
        o_acc[db] = __builtin_amdgcn_mfma_f32_32x32x16_bf16(af.v, vf[T][db], o_acc[db], 0, 0, 0);
      __builtin_amdgcn_s_setprio(0);
    }
    c ^= 1;
  }

  // epilogue: l broadcast via LDS, normalize, store
  {
    float lt = l_acc + __shfl_xor(l_acc, 32);
    Ls[wave][lh] = 1.0f / lt;
  }
  __builtin_amdgcn_wave_barrier();
  {
    f32x4 inv[4];
#pragma unroll
    for (int a = 0; a < 4; a++) inv[a] = *(const f32x4*)&Ls[wave][8 * a + 4 * hi];
#pragma unroll
    for (int db = 0; db < 2; db++) {
#pragma unroll
      for (int r = 0; r < 16; r++) {
        int srow = (r & 3) + 8 * (r >> 2) + 4 * hi;
        size_t o = (size_t)(b * 2048 + sBase + srow) * DM + qoff + db * 32 + lh;
        out[o] = f2bf(o_acc[db][r] * inv[r >> 2][r & 3]);
      }
    }
  }
}

extern "C" void kernel_launch(void* const* d_in, const int* in_sizes, int n_in,
                              void* d_out, int out_size, void* d_ws, size_t ws_size,
                              hipStream_t stream) {
  const float* q  = (const float*)d_in[0];
  const float* k  = (const float*)d_in[1];
  const float* v  = (const float*)d_in[2];
  const float* Wq = (const float*)d_in[3];
  const float* bq = (const float*)d_in[4];
  const float* Wk = (const float*)d_in[5];
  const float* bk = (const float*)d_in[6];
  const float* Wv = (const float*)d_in[7];
  const float* bv = (const float*)d_in[8];
  const float* Wo = (const float*)d_in[9];
  const float* bo = (const float*)d_in[10];

  u16* p = (u16*)d_ws;
  u16* WqkvT = p; p += (size_t)3072 * 2048;   // rows: 0-2047 Wq^T, 2048-2559 Wk^T, 2560-3071 Wv^T
  u16* WoT   = p; p += (size_t)2048 * 2048;
  u16* qb    = p; p += (size_t)4096 * 2048;   // bf16 casts of q/k/v; att aliases qb
  u16* kb    = p; p += (size_t)4096 * 2048;
  u16* vb    = p; p += (size_t)4096 * 2048;
  u16* qhb   = p; p += (size_t)4096 * 2048;
  u16* kvb   = p; p += (size_t)4096 * 1024;
  u16* vtb   = p; p += (size_t)16 * 64 * 2048;
  u16* att   = qb;  // reuse: qb dead after gemm_proj

  prep<<<dim3(14848), 256, 0, stream>>>(q, k, v, Wq, Wk, Wv, Wo, qb, kb, vb, WqkvT, WoT);

  gemm_proj<<<dim3(24, 32), 256, 0, stream>>>(qb, kb, vb, WqkvT, bq, bk, bv, qhb, kvb, vtb);

  attn2<<<dim3(16, 64), 256, 0, stream>>>(qhb, kvb, vtb, att);

  gemm_o<<<dim3(16, 32), 256, 0, stream>>>(att, WoT, bo, (float*)d_out);
}

// Round 9
// 395.637 us; speedup vs baseline: 3.3807x; 1.0376x over previous
//
#include <hip/hip_runtime.h>

typedef unsigned short u16;
typedef unsigned int u32;
typedef __attribute__((ext_vector_type(8))) short bf16x8;
typedef __attribute__((ext_vector_type(4))) float f32x4;
typedef __attribute__((ext_vector_type(16))) float f32x16;

#define DM 2048
#define SQ_SCALE (0.125f * 1.44269504089f)

__device__ __forceinline__ u16 f2bf(float f) {
  union { float f; u32 u; } v; v.f = f;
  u32 r = v.u + 0x7fffu + ((v.u >> 16) & 1u);
  return (u16)(r >> 16);
}
// pack two floats to (bf16(hi)<<16)|bf16(lo), round-half-up
__device__ __forceinline__ u32 pkrn(float lo, float hi) {
  union { float f; u32 u; } a, b; a.f = lo; b.f = hi;
  return ((a.u + 0x8000u) >> 16) | ((b.u + 0x8000u) & 0xffff0000u);
}
// hw packed cvt: dst = {bf16(lo) in [15:0], bf16(hi) in [31:16]} (RNE)
__device__ __forceinline__ u32 cvtpk(float lo, float hi) {
  u32 r;
  asm("v_cvt_pk_bf16_f32 %0, %1, %2" : "=v"(r) : "v"(lo), "v"(hi));
  return r;
}
__device__ __forceinline__ void gload16(const u16* g, u16* l) {
  __builtin_amdgcn_global_load_lds((const __attribute__((address_space(1))) void*)g,
                                   (__attribute__((address_space(3))) void*)l, 16, 0, 0);
}

// Merged preprocessing: one launch.
// blocks [0,12288): fp32->bf16 cast of q/k/v (4096 blocks each)
// blocks [12288,14848): W transposes -> bf16 [N][K] (Wq 1024, Wk 256, Wv 256, Wo 1024)
__global__ __launch_bounds__(256) void prep(const float* __restrict__ q,
                                            const float* __restrict__ k,
                                            const float* __restrict__ v,
                                            const float* __restrict__ Wq,
                                            const float* __restrict__ Wk,
                                            const float* __restrict__ Wv,
                                            const float* __restrict__ Wo,
                                            u16* __restrict__ qb,
                                            u16* __restrict__ kb,
                                            u16* __restrict__ vb,
                                            u16* __restrict__ WqkvT,
                                            u16* __restrict__ WoT) {
  __shared__ u16 s[64][72];
  int bid = blockIdx.x;
  if (bid < 12288) {
    int z = bid >> 12, x = bid & 4095;
    const float* in = (z == 0) ? q : (z == 1) ? k : v;
    u16* out = (z == 0) ? qb : (z == 1) ? kb : vb;
    size_t i = ((size_t)x * 256 + threadIdx.x) * 8;
    float4 f0 = *(const float4*)(in + i);
    float4 f1 = *(const float4*)(in + i + 4);
    uint4 w = {pkrn(f0.x, f0.y), pkrn(f0.z, f0.w), pkrn(f1.x, f1.y), pkrn(f1.z, f1.w)};
    *(uint4*)(out + i) = w;
    return;
  }
  int off = bid - 12288;
  const float* in; u16* out; int K, N, bx, by;
  if (off < 1024)      { in = Wq; out = WqkvT;                          K = 2048; N = 2048; bx = off & 31; by = off >> 5; }
  else if (off < 1280) { int i2 = off - 1024; in = Wk; out = WqkvT + (size_t)2048 * 2048; K = 2048; N = 512; bx = i2 & 7; by = i2 >> 3; }
  else if (off < 1536) { int i2 = off - 1280; in = Wv; out = WqkvT + (size_t)2560 * 2048; K = 2048; N = 512; bx = i2 & 7; by = i2 >> 3; }
  else                 { int i2 = off - 1536; in = Wo; out = WoT;       K = 2048; N = 2048; bx = i2 & 31; by = i2 >> 5; }
  int n0 = bx * 64, k0 = by * 64;
  int t = threadIdx.x;
  int r = t >> 2;
  int cc = (t & 3) * 16;
  const float* ip = in + (size_t)(k0 + r) * N + n0 + cc;
  u16 tmp[16];
#pragma unroll
  for (int i = 0; i < 16; i += 4) {
    float4 vv = *(const float4*)(ip + i);
    tmp[i] = f2bf(vv.x); tmp[i + 1] = f2bf(vv.y);
    tmp[i + 2] = f2bf(vv.z); tmp[i + 3] = f2bf(vv.w);
  }
  *(uint4*)&s[r][cc] = *(uint4*)tmp;
  *(uint4*)&s[r][cc + 8] = *(uint4*)(tmp + 8);
  __syncthreads();
#pragma unroll
  for (int i = 0; i < 16; i++) tmp[i] = s[cc + i][r];
  u16* op = out + (size_t)(n0 + r) * K + k0 + cc;
  *(uint4*)op = *(uint4*)tmp;
  *(uint4*)(op + 8) = *(uint4*)(tmp + 8);
}

// Fused QKV projection, BK=64 (two 32-col LDS buffers per operand; read pattern
// identical to validated BK=32 -> same bank behavior; barriers per FLOP halved).
// N logical 3072: [0,2048) Q -> qhb (scaled), [2048,2560) K -> kvb,
// [2560,3072) V -> V^T directly to vtb[(b*8+g)*64+d][t] (transpose fused).
__global__ __launch_bounds__(256) void gemm_proj(const u16* __restrict__ qb,
                                                 const u16* __restrict__ kb,
                                                 const u16* __restrict__ vb,
                                                 const u16* __restrict__ Bt,
                                                 const float* __restrict__ bqp,
                                                 const float* __restrict__ bkp,
                                                 const float* __restrict__ bvp,
                                                 u16* __restrict__ qhb,
                                                 u16* __restrict__ kvb,
                                                 u16* __restrict__ vtb) {
  __shared__ u16 As[2][128 * 32];
  __shared__ u16 Bs[2][128 * 32];
  int n0 = blockIdx.x * 128, m0 = blockIdx.y * 128;
  const u16* A; const float* bias; u16* C; int cw, bofs; float esc;
  if (n0 < 2048)      { A = qb; bias = bqp; C = qhb; cw = 2048; bofs = 0;    esc = SQ_SCALE; }
  else if (n0 < 2560) { A = kb; bias = bkp; C = kvb; cw = 1024; bofs = 2048; esc = 1.0f; }
  else                { A = vb; bias = bvp; C = kvb; cw = 1024; bofs = 2560; esc = 1.0f; }
  int ccol0 = (n0 < 2048) ? n0 : (n0 - 2048);

  int tid = threadIdx.x, wave = tid >> 6, lane = tid & 63;
  int lq = lane & 15, quad = lane >> 4;
  int wm = (wave & 1) * 64, wn = (wave >> 1) * 64;

  f32x4 zero = {0.f, 0.f, 0.f, 0.f};
  f32x4 acc[4][4];
#pragma unroll
  for (int i = 0; i < 4; i++)
#pragma unroll
    for (int j = 0; j < 4; j++) acc[i][j] = zero;

  const u16* gA = A + (size_t)(m0 + wave * 16 + (lane >> 2)) * 2048 + (lane & 3) * 8;
  const u16* gB = Bt + (size_t)(n0 + wave * 16 + (lane >> 2)) * 2048 + (lane & 3) * 8;
  u16* lA0[2] = {&As[0][(wave * 16) * 32], &As[1][(wave * 16) * 32]};
  u16* lA1[2] = {&As[0][(64 + wave * 16) * 32], &As[1][(64 + wave * 16) * 32]};
  u16* lB0[2] = {&Bs[0][(wave * 16) * 32], &Bs[1][(wave * 16) * 32]};
  u16* lB1[2] = {&Bs[0][(64 + wave * 16) * 32], &Bs[1][(64 + wave * 16) * 32]};

  for (int k0 = 0; k0 < 2048; k0 += 64) {
    __syncthreads();
    gload16(gA + k0, lA0[0]);
    gload16(gA + (size_t)64 * 2048 + k0, lA1[0]);
    gload16(gA + k0 + 32, lA0[1]);
    gload16(gA + (size_t)64 * 2048 + k0 + 32, lA1[1]);
    gload16(gB + k0, lB0[0]);
    gload16(gB + (size_t)64 * 2048 + k0, lB1[0]);
    gload16(gB + k0 + 32, lB0[1]);
    gload16(gB + (size_t)64 * 2048 + k0 + 32, lB1[1]);
    __syncthreads();
#pragma unroll
    for (int hf = 0; hf < 2; hf++) {
      bf16x8 af[4], bf[4];
#pragma unroll
      for (int i = 0; i < 4; i++) af[i] = *(const bf16x8*)&As[hf][(wm + i * 16 + lq) * 32 + quad * 8];
#pragma unroll
      for (int j = 0; j < 4; j++) bf[j] = *(const bf16x8*)&Bs[hf][(wn + j * 16 + lq) * 32 + quad * 8];
#pragma unroll
      for (int i = 0; i < 4; i++)
#pragma unroll
        for (int j = 0; j < 4; j++)
          acc[i][j] = __builtin_amdgcn_mfma_f32_16x16x32_bf16(af[i], bf[j], acc[i][j], 0, 0, 0);
    }
  }
  if (n0 >= 2560) {
    // V: write V^T directly. col cv in [0,512) = g*64+d; rows are t.
#pragma unroll
    for (int j = 0; j < 4; j++) {
      int cv = (n0 - 2560) + wn + j * 16 + lq;
      float bvv = bias[cv];
      u16* vout = vtb + (size_t)cv * 2048;
#pragma unroll
      for (int i = 0; i < 4; i++) {
        int row = m0 + wm + i * 16 + quad * 4;
        int bb = row >> 11, tt = row & 2047;
        u16 w4[4];
#pragma unroll
        for (int rg = 0; rg < 4; rg++) w4[rg] = f2bf(acc[i][j][rg] + bvv);
        *(uint2*)(vout + (size_t)bb * 8 * 64 * 2048 + tt) = *(uint2*)w4;
      }
    }
  } else {
#pragma unroll
    for (int j = 0; j < 4; j++) {
      int nglob = n0 + wn + j * 16 + lq;
      float bv = bias[nglob - bofs];
      int col = ccol0 + wn + j * 16 + lq;
#pragma unroll
      for (int i = 0; i < 4; i++) {
#pragma unroll
        for (int rg = 0; rg < 4; rg++) {
          int row = m0 + wm + i * 16 + quad * 4 + rg;
          C[(size_t)row * cw + col] = f2bf((acc[i][j][rg] + bv) * esc);
        }
      }
    }
  }
}

// O projection: fp32 C out, BK=64 two-buffer (same scheme as gemm_proj)
__global__ __launch_bounds__(256) void gemm_o(const u16* __restrict__ A,
                                              const u16* __restrict__ Bt,
                                              const float* __restrict__ bias,
                                              float* __restrict__ C) {
  __shared__ u16 As[2][128 * 32];
  __shared__ u16 Bs[2][128 * 32];
  int n0 = blockIdx.x * 128, m0 = blockIdx.y * 128;
  int tid = threadIdx.x, wave = tid >> 6, lane = tid & 63;
  int lq = lane & 15, quad = lane >> 4;
  int wm = (wave & 1) * 64, wn = (wave >> 1) * 64;

  f32x4 zero = {0.f, 0.f, 0.f, 0.f};
  f32x4 acc[4][4];
#pragma unroll
  for (int i = 0; i < 4; i++)
#pragma unroll
    for (int j = 0; j < 4; j++) acc[i][j] = zero;

  const u16* gA = A + (size_t)(m0 + wave * 16 + (lane >> 2)) * 2048 + (lane & 3) * 8;
  const u16* gB = Bt + (size_t)(n0 + wave * 16 + (lane >> 2)) * 2048 + (lane & 3) * 8;
  u16* lA0[2] = {&As[0][(wave * 16) * 32], &As[1][(wave * 16) * 32]};
  u16* lA1[2] = {&As[0][(64 + wave * 16) * 32], &As[1][(64 + wave * 16) * 32]};
  u16* lB0[2] = {&Bs[0][(wave * 16) * 32], &Bs[1][(wave * 16) * 32]};
  u16* lB1[2] = {&Bs[0][(64 + wave * 16) * 32], &Bs[1][(64 + wave * 16) * 32]};

  for (int k0 = 0; k0 < 2048; k0 += 64) {
    __syncthreads();
    gload16(gA + k0, lA0[0]);
    gload16(gA + (size_t)64 * 2048 + k0, lA1[0]);
    gload16(gA + k0 + 32, lA0[1]);
    gload16(gA + (size_t)64 * 2048 + k0 + 32, lA1[1]);
    gload16(gB + k0, lB0[0]);
    gload16(gB + (size_t)64 * 2048 + k0, lB1[0]);
    gload16(gB + k0 + 32, lB0[1]);
    gload16(gB + (size_t)64 * 2048 + k0 + 32, lB1[1]);
    __syncthreads();
#pragma unroll
    for (int hf = 0; hf < 2; hf++) {
      bf16x8 af[4], bf[4];
#pragma unroll
      for (int i = 0; i < 4; i++) af[i] = *(const bf16x8*)&As[hf][(wm + i * 16 + lq) * 32 + quad * 8];
#pragma unroll
      for (int j = 0; j < 4; j++) bf[j] = *(const bf16x8*)&Bs[hf][(wn + j * 16 + lq) * 32 + quad * 8];
#pragma unroll
      for (int i = 0; i < 4; i++)
#pragma unroll
        for (int j = 0; j < 4; j++)
          acc[i][j] = __builtin_amdgcn_mfma_f32_16x16x32_bf16(af[i], bf[j], acc[i][j], 0, 0, 0);
    }
  }
#pragma unroll
  for (int j = 0; j < 4; j++) {
    int col = n0 + wn + j * 16 + lq;
    float bv = bias[col];
#pragma unroll
    for (int i = 0; i < 4; i++) {
#pragma unroll
      for (int rg = 0; rg < 4; rg++) {
        int row = m0 + wm + i * 16 + quad * 4 + rg;
        C[(size_t)row * 2048 + col] = acc[i][j][rg] + bv;
      }
    }
  }
}

// Flash attention v9 = R3's proven 2-barrier single-buffer schedule, TBLK=64:
// one staging round feeds TWO independent 32-t compute sub-tiles. Barriers per
// block halve (128->64); each barrier-to-barrier span has 2x independent work
// (two QK chains + two softmax chains) -> more ILP against the measured
// ~4200cyc/iter latency floor (R8: issue demand only ~800cyc/iter).
// LDS 18.9KB single-buffered; K/V read pattern = validated 4-way-benign.
__global__ __launch_bounds__(256) void attn2(const u16* __restrict__ qh,
                                             const u16* __restrict__ kvb,
                                             const u16* __restrict__ vtb,
                                             u16* __restrict__ out) {
  __shared__ u16 Ks[64][72];   // [t][d] rows 144B
  __shared__ u16 Vs[64][72];   // [d][t] rows 144B (t 0..63)
  __shared__ float Ls[4][32];
  int flat = blockIdx.x + (blockIdx.y << 4);
  int w = ((flat & 7) << 7) + (flat >> 3);   // bijective: 1024 blocks, 128/XCD
  int head = w >> 4;
  int b = head >> 5, g = (head >> 2) & 7, h = head & 3;
  int tid = threadIdx.x, wave = tid >> 6, lane = tid & 63;
  int lh = lane & 31, hi = lane >> 5;
  const int qoff = (g * 4 + h) * 64;
  const int koff = g * 64;
  int sBase = (w & 15) * 128 + wave * 32;

  // Q as B-operand (Q^T): lane n=s=lh, k=d = st*16 + hi*8 + j
  bf16x8 qf[4];
#pragma unroll
  for (int st = 0; st < 4; st++)
    qf[st] = *(const bf16x8*)(qh + (size_t)(b * 2048 + sBase + lh) * DM +
                              qoff + st * 16 + hi * 8);

  f32x16 o_acc[2];
#pragma unroll
  for (int db = 0; db < 2; db++)
#pragma unroll
    for (int r = 0; r < 16; r++) o_acc[db][r] = 0.f;
  float l_acc = 0.f;

  // staging: 64x64 tile, 16 u16 per thread per tensor
  int sr = tid >> 2, sc = (tid & 3) * 16;   // K: row t, col d
  const u16* kbase = kvb + (size_t)b * 2048 * 1024 + koff;
  const u16* vbase = vtb + (size_t)(head >> 2) * 64 * 2048 + (size_t)sr * 2048;

  uint4 kreg0 = *(const uint4*)(kbase + (size_t)sr * 1024 + sc);
  uint4 kreg1 = *(const uint4*)(kbase + (size_t)sr * 1024 + sc + 8);
  uint4 vreg0 = *(const uint4*)(vbase + sc);
  uint4 vreg1 = *(const uint4*)(vbase + sc + 8);

  for (int t0 = 0; t0 < 2048; t0 += 64) {
    __syncthreads();   // prior iter's LDS reads done
    *(uint4*)&Ks[sr][sc] = kreg0;
    *(uint4*)&Ks[sr][sc + 8] = kreg1;
    *(uint4*)&Vs[sr][sc] = vreg0;
    *(uint4*)&Vs[sr][sc + 8] = vreg1;
    __syncthreads();
    // prefetch next tile AFTER the barrier: latency hides under compute,
    // consumed at next iter's LDS write (which follows the next barrier)
    int tn = (t0 + 64 < 2048) ? t0 + 64 : 0;
    kreg0 = *(const uint4*)(kbase + (size_t)(tn + sr) * 1024 + sc);
    kreg1 = *(const uint4*)(kbase + (size_t)(tn + sr) * 1024 + sc + 8);
    vreg0 = *(const uint4*)(vbase + tn + sc);
    vreg1 = *(const uint4*)(vbase + tn + sc + 8);

#pragma unroll
    for (int u = 0; u < 2; u++) {
      bf16x8 kf[4];
#pragma unroll
      for (int st = 0; st < 4; st++)
        kf[st] = *(const bf16x8*)&Ks[u * 32 + lh][st * 16 + hi * 8];

      f32x16 st_acc;
#pragma unroll
      for (int r = 0; r < 16; r++) st_acc[r] = 0.f;
      __builtin_amdgcn_s_setprio(1);
#pragma unroll
      for (int st = 0; st < 4; st++)
        st_acc = __builtin_amdgcn_mfma_f32_32x32x16_bf16(kf[st], qf[st], st_acc, 0, 0, 0);
      __builtin_amdgcn_s_setprio(0);
      // S^T: lane holds col s=lh, rows t_local=(r&3)+8*(r>>2)+4*hi
      float pr[16];
#pragma unroll
      for (int r = 0; r < 16; r++) pr[r] = __builtin_amdgcn_exp2f(st_acc[r]);
      float s0 = ((pr[0] + pr[1]) + (pr[2] + pr[3])) + ((pr[4] + pr[5]) + (pr[6] + pr[7]));
      float s1 = ((pr[8] + pr[9]) + (pr[10] + pr[11])) + ((pr[12] + pr[13]) + (pr[14] + pr[15]));
      l_acc += s0 + s1;
      u32 pk[8];
#pragma unroll
      for (int a = 0; a < 4; a++) {
        pk[2 * a] = cvtpk(pr[4 * a], pr[4 * a + 1]);
        pk[2 * a + 1] = cvtpk(pr[4 * a + 2], pr[4 * a + 3]);
      }
#pragma unroll
      for (int T2 = 0; T2 < 2; T2++) {
        // A-operand for PV needs t_local = 16*T2 + 8*hi + j; exchange via xor-32
        u32 E0 = hi ? pk[4 * T2] : pk[4 * T2 + 2];
        u32 E1 = hi ? pk[4 * T2 + 1] : pk[4 * T2 + 3];
        u32 X0 = __shfl_xor(E0, 32);
        u32 X1 = __shfl_xor(E1, 32);
        union { u32 u[4]; bf16x8 v; } af;
        af.u[0] = hi ? X0 : pk[4 * T2];
        af.u[1] = hi ? X1 : pk[4 * T2 + 1];
        af.u[2] = hi ? pk[4 * T2 + 2] : X0;
        af.u[3] = hi ? pk[4 * T2 + 3] : X1;
        bf16x8 vf[2];
#pragma unroll
        for (int db = 0; db < 2; db++)
          vf[db] = *(const bf16x8*)&Vs[db * 32 + lh][u * 32 + T2 * 16 + hi * 8];
        __builtin_amdgcn_s_setprio(1);
#pragma unroll
        for (int db = 0; db < 2; db++)
          o_acc[db] = __builtin_amdgcn_mfma_f32_32x32x16_bf16(af.v, vf[db], o_acc[db], 0, 0, 0);
        __builtin_amdgcn_s_setprio(0);
      }
    }
  }

  // epilogue: l broadcast via LDS, normalize, store
  {
    float lt = l_acc + __shfl_xor(l_acc, 32);
    Ls[wave][lh] = 1.0f / lt;
  }
  __builtin_amdgcn_wave_barrier();
  {
    f32x4 inv[4];
#pragma unroll
    for (int a = 0; a < 4; a++) inv[a] = *(const f32x4*)&Ls[wave][8 * a + 4 * hi];
#pragma unroll
    for (int db = 0; db < 2; db++) {
#pragma unroll
      for (int r = 0; r < 16; r++) {
        int srow = (r & 3) + 8 * (r >> 2) + 4 * hi;
        size_t o = (size_t)(b * 2048 + sBase + srow) * DM + qoff + db * 32 + lh;
        out[o] = f2bf(o_acc[db][r] * inv[r >> 2][r & 3]);
      }
    }
  }
}

extern "C" void kernel_launch(void* const* d_in, const int* in_sizes, int n_in,
                              void* d_out, int out_size, void* d_ws, size_t ws_size,
                              hipStream_t stream) {
  const float* q  = (const float*)d_in[0];
  const float* k  = (const float*)d_in[1];
  const float* v  = (const float*)d_in[2];
  const float* Wq = (const float*)d_in[3];
  const float* bq = (const float*)d_in[4];
  const float* Wk = (const float*)d_in[5];
  const float* bk = (const float*)d_in[6];
  const float* Wv = (const float*)d_in[7];
  const float* bv = (const float*)d_in[8];
  const float* Wo = (const float*)d_in[9];
  const float* bo = (const float*)d_in[10];

  u16* p = (u16*)d_ws;
  u16* WqkvT = p; p += (size_t)3072 * 2048;   // rows: 0-2047 Wq^T, 2048-2559 Wk^T, 2560-3071 Wv^T
  u16* WoT   = p; p += (size_t)2048 * 2048;
  u16* qb    = p; p += (size_t)4096 * 2048;   // bf16 casts of q/k/v; att aliases qb
  u16* kb    = p; p += (size_t)4096 * 2048;
  u16* vb    = p; p += (size_t)4096 * 2048;
  u16* qhb   = p; p += (size_t)4096 * 2048;
  u16* kvb   = p; p += (size_t)4096 * 1024;
  u16* vtb   = p; p += (size_t)16 * 64 * 2048;
  u16* att   = qb;  // reuse: qb dead after gemm_proj

  prep<<<dim3(14848), 256, 0, stream>>>(q, k, v, Wq, Wk, Wv, Wo, qb, kb, vb, WqkvT, WoT);

  gemm_proj<<<dim3(24, 32), 256, 0, stream>>>(qb, kb, vb, WqkvT, bq, bk, bv, qhb, kvb, vtb);

  attn2<<<dim3(16, 64), 256, 0, stream>>>(qhb, kvb, vtb, att);

  gemm_o<<<dim3(16, 32), 256, 0, stream>>>(att, WoT, bo, (float*)d_out);
}

// Round 10
// 395.284 us; speedup vs baseline: 3.3837x; 1.0009x over previous
//
#include <hip/hip_runtime.h>

typedef unsigned short u16;
typedef unsigned int u32;
typedef __attribute__((ext_vector_type(8))) short bf16x8;
typedef __attribute__((ext_vector_type(4))) float f32x4;
typedef __attribute__((ext_vector_type(16))) float f32x16;

#define DM 2048
#define SQ_SCALE (0.125f * 1.44269504089f)

__device__ __forceinline__ u16 f2bf(float f) {
  union { float f; u32 u; } v; v.f = f;
  u32 r = v.u + 0x7fffu + ((v.u >> 16) & 1u);
  return (u16)(r >> 16);
}
// pack two floats to (bf16(hi)<<16)|bf16(lo), round-half-up
__device__ __forceinline__ u32 pkrn(float lo, float hi) {
  union { float f; u32 u; } a, b; a.f = lo; b.f = hi;
  return ((a.u + 0x8000u) >> 16) | ((b.u + 0x8000u) & 0xffff0000u);
}
// hw packed cvt: dst = {bf16(lo) in [15:0], bf16(hi) in [31:16]} (RNE)
__device__ __forceinline__ u32 cvtpk(float lo, float hi) {
  u32 r;
  asm("v_cvt_pk_bf16_f32 %0, %1, %2" : "=v"(r) : "v"(lo), "v"(hi));
  return r;
}
__device__ __forceinline__ void gload16(const u16* g, u16* l) {
  __builtin_amdgcn_global_load_lds((const __attribute__((address_space(1))) void*)g,
                                   (__attribute__((address_space(3))) void*)l, 16, 0, 0);
}

// Merged preprocessing: one launch.
// blocks [0,12288): fp32->bf16 cast of q/k/v (4096 blocks each)
// blocks [12288,14848): W transposes -> bf16 [N][K] (Wq 1024, Wk 256, Wv 256, Wo 1024)
__global__ __launch_bounds__(256) void prep(const float* __restrict__ q,
                                            const float* __restrict__ k,
                                            const float* __restrict__ v,
                                            const float* __restrict__ Wq,
                                            const float* __restrict__ Wk,
                                            const float* __restrict__ Wv,
                                            const float* __restrict__ Wo,
                                            u16* __restrict__ qb,
                                            u16* __restrict__ kb,
                                            u16* __restrict__ vb,
                                            u16* __restrict__ WqkvT,
                                            u16* __restrict__ WoT) {
  __shared__ u16 s[64][72];
  int bid = blockIdx.x;
  if (bid < 12288) {
    int z = bid >> 12, x = bid & 4095;
    const float* in = (z == 0) ? q : (z == 1) ? k : v;
    u16* out = (z == 0) ? qb : (z == 1) ? kb : vb;
    size_t i = ((size_t)x * 256 + threadIdx.x) * 8;
    float4 f0 = *(const float4*)(in + i);
    float4 f1 = *(const float4*)(in + i + 4);
    uint4 w = {pkrn(f0.x, f0.y), pkrn(f0.z, f0.w), pkrn(f1.x, f1.y), pkrn(f1.z, f1.w)};
    *(uint4*)(out + i) = w;
    return;
  }
  int off = bid - 12288;
  const float* in; u16* out; int K, N, bx, by;
  if (off < 1024)      { in = Wq; out = WqkvT;                          K = 2048; N = 2048; bx = off & 31; by = off >> 5; }
  else if (off < 1280) { int i2 = off - 1024; in = Wk; out = WqkvT + (size_t)2048 * 2048; K = 2048; N = 512; bx = i2 & 7; by = i2 >> 3; }
  else if (off < 1536) { int i2 = off - 1280; in = Wv; out = WqkvT + (size_t)2560 * 2048; K = 2048; N = 512; bx = i2 & 7; by = i2 >> 3; }
  else                 { int i2 = off - 1536; in = Wo; out = WoT;       K = 2048; N = 2048; bx = i2 & 31; by = i2 >> 5; }
  int n0 = bx * 64, k0 = by * 64;
  int t = threadIdx.x;
  int r = t >> 2;
  int cc = (t & 3) * 16;
  const float* ip = in + (size_t)(k0 + r) * N + n0 + cc;
  u16 tmp[16];
#pragma unroll
  for (int i = 0; i < 16; i += 4) {
    float4 vv = *(const float4*)(ip + i);
    tmp[i] = f2bf(vv.x); tmp[i + 1] = f2bf(vv.y);
    tmp[i + 2] = f2bf(vv.z); tmp[i + 3] = f2bf(vv.w);
  }
  *(uint4*)&s[r][cc] = *(uint4*)tmp;
  *(uint4*)&s[r][cc + 8] = *(uint4*)(tmp + 8);
  __syncthreads();
#pragma unroll
  for (int i = 0; i < 16; i++) tmp[i] = s[cc + i][r];
  u16* op = out + (size_t)(n0 + r) * K + k0 + cc;
  *(uint4*)op = *(uint4*)tmp;
  *(uint4*)(op + 8) = *(uint4*)(tmp + 8);
}

// Fused QKV projection, BK=64 (two 32-col LDS buffers per operand; read pattern
// identical to validated BK=32 -> same bank behavior; barriers per FLOP halved).
// N logical 3072: [0,2048) Q -> qhb (scaled), [2048,2560) K -> kvb,
// [2560,3072) V -> V^T directly to vtb[(b*8+g)*64+d][t] (transpose fused).
__global__ __launch_bounds__(256) void gemm_proj(const u16* __restrict__ qb,
                                                 const u16* __restrict__ kb,
                                                 const u16* __restrict__ vb,
                                                 const u16* __restrict__ Bt,
                                                 const float* __restrict__ bqp,
                                                 const float* __restrict__ bkp,
                                                 const float* __restrict__ bvp,
                                                 u16* __restrict__ qhb,
                                                 u16* __restrict__ kvb,
                                                 u16* __restrict__ vtb) {
  __shared__ u16 As[2][128 * 32];
  __shared__ u16 Bs[2][128 * 32];
  int n0 = blockIdx.x * 128, m0 = blockIdx.y * 128;
  const u16* A; const float* bias; u16* C; int cw, bofs; float esc;
  if (n0 < 2048)      { A = qb; bias = bqp; C = qhb; cw = 2048; bofs = 0;    esc = SQ_SCALE; }
  else if (n0 < 2560) { A = kb; bias = bkp; C = kvb; cw = 1024; bofs = 2048; esc = 1.0f; }
  else                { A = vb; bias = bvp; C = kvb; cw = 1024; bofs = 2560; esc = 1.0f; }
  int ccol0 = (n0 < 2048) ? n0 : (n0 - 2048);

  int tid = threadIdx.x, wave = tid >> 6, lane = tid & 63;
  int lq = lane & 15, quad = lane >> 4;
  int wm = (wave & 1) * 64, wn = (wave >> 1) * 64;

  f32x4 zero = {0.f, 0.f, 0.f, 0.f};
  f32x4 acc[4][4];
#pragma unroll
  for (int i = 0; i < 4; i++)
#pragma unroll
    for (int j = 0; j < 4; j++) acc[i][j] = zero;

  const u16* gA = A + (size_t)(m0 + wave * 16 + (lane >> 2)) * 2048 + (lane & 3) * 8;
  const u16* gB = Bt + (size_t)(n0 + wave * 16 + (lane >> 2)) * 2048 + (lane & 3) * 8;
  u16* lA0[2] = {&As[0][(wave * 16) * 32], &As[1][(wave * 16) * 32]};
  u16* lA1[2] = {&As[0][(64 + wave * 16) * 32], &As[1][(64 + wave * 16) * 32]};
  u16* lB0[2] = {&Bs[0][(wave * 16) * 32], &Bs[1][(wave * 16) * 32]};
  u16* lB1[2] = {&Bs[0][(64 + wave * 16) * 32], &Bs[1][(64 + wave * 16) * 32]};

  for (int k0 = 0; k0 < 2048; k0 += 64) {
    __syncthreads();
    gload16(gA + k0, lA0[0]);
    gload16(gA + (size_t)64 * 2048 + k0, lA1[0]);
    gload16(gA + k0 + 32, lA0[1]);
    gload16(gA + (size_t)64 * 2048 + k0 + 32, lA1[1]);
    gload16(gB + k0, lB0[0]);
    gload16(gB + (size_t)64 * 2048 + k0, lB1[0]);
    gload16(gB + k0 + 32, lB0[1]);
    gload16(gB + (size_t)64 * 2048 + k0 + 32, lB1[1]);
    __syncthreads();
#pragma unroll
    for (int hf = 0; hf < 2; hf++) {
      bf16x8 af[4], bf[4];
#pragma unroll
      for (int i = 0; i < 4; i++) af[i] = *(const bf16x8*)&As[hf][(wm + i * 16 + lq) * 32 + quad * 8];
#pragma unroll
      for (int j = 0; j < 4; j++) bf[j] = *(const bf16x8*)&Bs[hf][(wn + j * 16 + lq) * 32 + quad * 8];
#pragma unroll
      for (int i = 0; i < 4; i++)
#pragma unroll
        for (int j = 0; j < 4; j++)
          acc[i][j] = __builtin_amdgcn_mfma_f32_16x16x32_bf16(af[i], bf[j], acc[i][j], 0, 0, 0);
    }
  }
  if (n0 >= 2560) {
    // V: write V^T directly. col cv in [0,512) = g*64+d; rows are t.
#pragma unroll
    for (int j = 0; j < 4; j++) {
      int cv = (n0 - 2560) + wn + j * 16 + lq;
      float bvv = bias[cv];
      u16* vout = vtb + (size_t)cv * 2048;
#pragma unroll
      for (int i = 0; i < 4; i++) {
        int row = m0 + wm + i * 16 + quad * 4;
        int bb = row >> 11, tt = row & 2047;
        u16 w4[4];
#pragma unroll
        for (int rg = 0; rg < 4; rg++) w4[rg] = f2bf(acc[i][j][rg] + bvv);
        *(uint2*)(vout + (size_t)bb * 8 * 64 * 2048 + tt) = *(uint2*)w4;
      }
    }
  } else {
#pragma unroll
    for (int j = 0; j < 4; j++) {
      int nglob = n0 + wn + j * 16 + lq;
      float bv = bias[nglob - bofs];
      int col = ccol0 + wn + j * 16 + lq;
#pragma unroll
      for (int i = 0; i < 4; i++) {
#pragma unroll
        for (int rg = 0; rg < 4; rg++) {
          int row = m0 + wm + i * 16 + quad * 4 + rg;
          C[(size_t)row * cw + col] = f2bf((acc[i][j][rg] + bv) * esc);
        }
      }
    }
  }
}

// O projection: fp32 C out, BK=64 two-buffer (same scheme as gemm_proj)
__global__ __launch_bounds__(256) void gemm_o(const u16* __restrict__ A,
                                              const u16* __restrict__ Bt,
                                              const float* __restrict__ bias,
                                              float* __restrict__ C) {
  __shared__ u16 As[2][128 * 32];
  __shared__ u16 Bs[2][128 * 32];
  int n0 = blockIdx.x * 128, m0 = blockIdx.y * 128;
  int tid = threadIdx.x, wave = tid >> 6, lane = tid & 63;
  int lq = lane & 15, quad = lane >> 4;
  int wm = (wave & 1) * 64, wn = (wave >> 1) * 64;

  f32x4 zero = {0.f, 0.f, 0.f, 0.f};
  f32x4 acc[4][4];
#pragma unroll
  for (int i = 0; i < 4; i++)
#pragma unroll
    for (int j = 0; j < 4; j++) acc[i][j] = zero;

  const u16* gA = A + (size_t)(m0 + wave * 16 + (lane >> 2)) * 2048 + (lane & 3) * 8;
  const u16* gB = Bt + (size_t)(n0 + wave * 16 + (lane >> 2)) * 2048 + (lane & 3) * 8;
  u16* lA0[2] = {&As[0][(wave * 16) * 32], &As[1][(wave * 16) * 32]};
  u16* lA1[2] = {&As[0][(64 + wave * 16) * 32], &As[1][(64 + wave * 16) * 32]};
  u16* lB0[2] = {&Bs[0][(wave * 16) * 32], &Bs[1][(wave * 16) * 32]};
  u16* lB1[2] = {&Bs[0][(64 + wave * 16) * 32], &Bs[1][(64 + wave * 16) * 32]};

  for (int k0 = 0; k0 < 2048; k0 += 64) {
    __syncthreads();
    gload16(gA + k0, lA0[0]);
    gload16(gA + (size_t)64 * 2048 + k0, lA1[0]);
    gload16(gA + k0 + 32, lA0[1]);
    gload16(gA + (size_t)64 * 2048 + k0 + 32, lA1[1]);
    gload16(gB + k0, lB0[0]);
    gload16(gB + (size_t)64 * 2048 + k0, lB1[0]);
    gload16(gB + k0 + 32, lB0[1]);
    gload16(gB + (size_t)64 * 2048 + k0 + 32, lB1[1]);
    __syncthreads();
#pragma unroll
    for (int hf = 0; hf < 2; hf++) {
      bf16x8 af[4], bf[4];
#pragma unroll
      for (int i = 0; i < 4; i++) af[i] = *(const bf16x8*)&As[hf][(wm + i * 16 + lq) * 32 + quad * 8];
#pragma unroll
      for (int j = 0; j < 4; j++) bf[j] = *(const bf16x8*)&Bs[hf][(wn + j * 16 + lq) * 32 + quad * 8];
#pragma unroll
      for (int i = 0; i < 4; i++)
#pragma unroll
        for (int j = 0; j < 4; j++)
          acc[i][j] = __builtin_amdgcn_mfma_f32_16x16x32_bf16(af[i], bf[j], acc[i][j], 0, 0, 0);
    }
  }
#pragma unroll
  for (int j = 0; j < 4; j++) {
    int col = n0 + wn + j * 16 + lq;
    float bv = bias[col];
#pragma unroll
    for (int i = 0; i < 4; i++) {
#pragma unroll
      for (int rg = 0; rg < 4; rg++) {
        int row = m0 + wm + i * 16 + quad * 4 + rg;
        C[(size_t)row * 2048 + col] = acc[i][j][rg] + bv;
      }
    }
  }
}

// Flash attention v10 = R9 (TBLK=64, 2-barrier, zero-conflict) with the xor-32
// exchange replaced by v_permlane32_swap_b32 (T12 primitive). R9 counters show
// attn2 is ISSUE-bound (VALU 48% + Mfma 29% + trans + LDS ~ saturation), so cut
// instructions: per subtile, 4 ds_bpermute + 16 cndmask -> 4 permlane ops.
// Mapping (verified): swap(a,b) -> a'={a.row0,b.row0}, b'={a.row1,b.row1};
// (af0,af2)=swap(pk0,pk2), (af1,af3)=swap(pk1,pk3) gives rows t=16T+8hi+j.
__global__ __launch_bounds__(256) void attn2(const u16* __restrict__ qh,
                                             const u16* __restrict__ kvb,
                                             const u16* __restrict__ vtb,
                                             u16* __restrict__ out) {
  __shared__ u16 Ks[64][72];   // [t][d] rows 144B
  __shared__ u16 Vs[64][72];   // [d][t] rows 144B (t 0..63)
  __shared__ float Ls[4][32];
  int flat = blockIdx.x + (blockIdx.y << 4);
  int w = ((flat & 7) << 7) + (flat >> 3);   // bijective: 1024 blocks, 128/XCD
  int head = w >> 4;
  int b = head >> 5, g = (head >> 2) & 7, h = head & 3;
  int tid = threadIdx.x, wave = tid >> 6, lane = tid & 63;
  int lh = lane & 31, hi = lane >> 5;
  const int qoff = (g * 4 + h) * 64;
  const int koff = g * 64;
  int sBase = (w & 15) * 128 + wave * 32;

  // Q as B-operand (Q^T): lane n=s=lh, k=d = st*16 + hi*8 + j
  bf16x8 qf[4];
#pragma unroll
  for (int st = 0; st < 4; st++)
    qf[st] = *(const bf16x8*)(qh + (size_t)(b * 2048 + sBase + lh) * DM +
                              qoff + st * 16 + hi * 8);

  f32x16 o_acc[2];
#pragma unroll
  for (int db = 0; db < 2; db++)
#pragma unroll
    for (int r = 0; r < 16; r++) o_acc[db][r] = 0.f;
  float l_acc = 0.f;

  // staging: 64x64 tile, 16 u16 per thread per tensor
  int sr = tid >> 2, sc = (tid & 3) * 16;   // K: row t, col d
  const u16* kbase = kvb + (size_t)b * 2048 * 1024 + koff;
  const u16* vbase = vtb + (size_t)(head >> 2) * 64 * 2048 + (size_t)sr * 2048;

  uint4 kreg0 = *(const uint4*)(kbase + (size_t)sr * 1024 + sc);
  uint4 kreg1 = *(const uint4*)(kbase + (size_t)sr * 1024 + sc + 8);
  uint4 vreg0 = *(const uint4*)(vbase + sc);
  uint4 vreg1 = *(const uint4*)(vbase + sc + 8);

  for (int t0 = 0; t0 < 2048; t0 += 64) {
    __syncthreads();   // prior iter's LDS reads done
    *(uint4*)&Ks[sr][sc] = kreg0;
    *(uint4*)&Ks[sr][sc + 8] = kreg1;
    *(uint4*)&Vs[sr][sc] = vreg0;
    *(uint4*)&Vs[sr][sc + 8] = vreg1;
    __syncthreads();
    // prefetch next tile AFTER the barrier: latency hides under compute,
    // consumed at next iter's LDS write (which follows the next barrier)
    int tn = (t0 + 64 < 2048) ? t0 + 64 : 0;
    kreg0 = *(const uint4*)(kbase + (size_t)(tn + sr) * 1024 + sc);
    kreg1 = *(const uint4*)(kbase + (size_t)(tn + sr) * 1024 + sc + 8);
    vreg0 = *(const uint4*)(vbase + tn + sc);
    vreg1 = *(const uint4*)(vbase + tn + sc + 8);

#pragma unroll
    for (int u = 0; u < 2; u++) {
      bf16x8 kf[4];
#pragma unroll
      for (int st = 0; st < 4; st++)
        kf[st] = *(const bf16x8*)&Ks[u * 32 + lh][st * 16 + hi * 8];

      f32x16 st_acc;
#pragma unroll
      for (int r = 0; r < 16; r++) st_acc[r] = 0.f;
      __builtin_amdgcn_s_setprio(1);
#pragma unroll
      for (int st = 0; st < 4; st++)
        st_acc = __builtin_amdgcn_mfma_f32_32x32x16_bf16(kf[st], qf[st], st_acc, 0, 0, 0);
      __builtin_amdgcn_s_setprio(0);
      // S^T: lane holds col s=lh, rows t_local=(r&3)+8*(r>>2)+4*hi
      float pr[16];
#pragma unroll
      for (int r = 0; r < 16; r++) pr[r] = __builtin_amdgcn_exp2f(st_acc[r]);
      float s0 = ((pr[0] + pr[1]) + (pr[2] + pr[3])) + ((pr[4] + pr[5]) + (pr[6] + pr[7]));
      float s1 = ((pr[8] + pr[9]) + (pr[10] + pr[11])) + ((pr[12] + pr[13]) + (pr[14] + pr[15]));
      l_acc += s0 + s1;
      u32 pk[8];
#pragma unroll
      for (int a = 0; a < 4; a++) {
        pk[2 * a] = cvtpk(pr[4 * a], pr[4 * a + 1]);
        pk[2 * a + 1] = cvtpk(pr[4 * a + 2], pr[4 * a + 3]);
      }
#pragma unroll
      for (int T2 = 0; T2 < 2; T2++) {
        // A-operand rows t_local = 16*T2 + 8*hi + j via permlane32_swap:
        // w0'={pk0.row0, pk2.row0} = af0; w2'={pk0.row1, pk2.row1} = af2
        u32 w0 = pk[4 * T2], w1 = pk[4 * T2 + 1];
        u32 w2 = pk[4 * T2 + 2], w3 = pk[4 * T2 + 3];
        asm("v_permlane32_swap_b32 %0, %1" : "+v"(w0), "+v"(w2));
        asm("v_permlane32_swap_b32 %0, %1" : "+v"(w1), "+v"(w3));
        union { u32 u[4]; bf16x8 v; } af;
        af.u[0] = w0; af.u[1] = w1; af.u[2] = w2; af.u[3] = w3;
        bf16x8 vf[2];
#pragma unroll
        for (int db = 0; db < 2; db++)
          vf[db] = *(const bf16x8*)&Vs[db * 32 + lh][u * 32 + T2 * 16 + hi * 8];
        __builtin_amdgcn_s_setprio(1);
#pragma unroll
        for (int db = 0; db < 2; db++)
          o_acc[db] = __builtin_amdgcn_mfma_f32_32x32x16_bf16(af.v, vf[db], o_acc[db], 0, 0, 0);
        __builtin_amdgcn_s_setprio(0);
      }
    }
  }

  // epilogue: l broadcast via LDS, normalize, store
  {
    float lt = l_acc + __shfl_xor(l_acc, 32);
    Ls[wave][lh] = 1.0f / lt;
  }
  __builtin_amdgcn_wave_barrier();
  {
    f32x4 inv[4];
#pragma unroll
    for (int a = 0; a < 4; a++) inv[a] = *(const f32x4*)&Ls[wave][8 * a + 4 * hi];
#pragma unroll
    for (int db = 0; db < 2; db++) {
#pragma unroll
      for (int r = 0; r < 16; r++) {
        int srow = (r & 3) + 8 * (r >> 2) + 4 * hi;
        size_t o = (size_t)(b * 2048 + sBase + srow) * DM + qoff + db * 32 + lh;
        out[o] = f2bf(o_acc[db][r] * inv[r >> 2][r & 3]);
      }
    }
  }
}

extern "C" void kernel_launch(void* const* d_in, const int* in_sizes, int n_in,
                              void* d_out, int out_size, void* d_ws, size_t ws_size,
                              hipStream_t stream) {
  const float* q  = (const float*)d_in[0];
  const float* k  = (const float*)d_in[1];
  const float* v  = (const float*)d_in[2];
  const float* Wq = (const float*)d_in[3];
  const float* bq = (const float*)d_in[4];
  const float* Wk = (const float*)d_in[5];
  const float* bk = (const float*)d_in[6];
  const float* Wv = (const float*)d_in[7];
  const float* bv = (const float*)d_in[8];
  const float* Wo = (const float*)d_in[9];
  const float* bo = (const float*)d_in[10];

  u16* p = (u16*)d_ws;
  u16* WqkvT = p; p += (size_t)3072 * 2048;   // rows: 0-2047 Wq^T, 2048-2559 Wk^T, 2560-3071 Wv^T
  u16* WoT   = p; p += (size_t)2048 * 2048;
  u16* qb    = p; p += (size_t)4096 * 2048;   // bf16 casts of q/k/v; att aliases qb
  u16* kb    = p; p += (size_t)4096 * 2048;
  u16* vb    = p; p += (size_t)4096 * 2048;
  u16* qhb   = p; p += (size_t)4096 * 2048;
  u16* kvb   = p; p += (size_t)4096 * 1024;
  u16* vtb   = p; p += (size_t)16 * 64 * 2048;
  u16* att   = qb;  // reuse: qb dead after gemm_proj

  prep<<<dim3(14848), 256, 0, stream>>>(q, k, v, Wq, Wk, Wv, Wo, qb, kb, vb, WqkvT, WoT);

  gemm_proj<<<dim3(24, 32), 256, 0, stream>>>(qb, kb, vb, WqkvT, bq, bk, bv, qhb, kvb, vtb);

  attn2<<<dim3(16, 64), 256, 0, stream>>>(qhb, kvb, vtb, att);

  gemm_o<<<dim3(16, 32), 256, 0, stream>>>(att, WoT, bo, (float*)d_out);
}